// Round 16
// baseline (1046.562 us; speedup 1.0000x reference)
//
#include <hip/hip_runtime.h>
#include <hip/hip_bf16.h>

typedef unsigned short u16;
typedef __attribute__((ext_vector_type(8))) short bf16x8;
typedef __attribute__((ext_vector_type(4))) float f32x4;
typedef __attribute__((ext_vector_type(8))) unsigned short u16x8;
typedef __attribute__((ext_vector_type(4))) unsigned short u16x4;

#define T_TOK 1024
#define HID 2048
#define HEADS 16
#define Q_LORA 1536
#define KV_LORA 512
#define NOPE 128
#define ROPED 64
#define VD 128
#define N_EXP 8
#define MOE_I 1408
#define SH_I 2816
#define QKV_N 2112
#define QKV_LD 2176
#define QD 192
#define KVD 256
#define EPSF 1e-6f
#define NEG_BIG (-3.4e38f)

__device__ __forceinline__ u16 f2bf(float f) {
  union { float f; unsigned u; } x; x.f = f;
  unsigned r = x.u + 0x7fffu + ((x.u >> 16) & 1u);
  return (u16)(r >> 16);
}
__device__ __forceinline__ float bf2f(u16 h) {
  union { unsigned u; float f; } x; x.u = ((unsigned)h) << 16; return x.f;
}
__device__ __forceinline__ void split2(float f, u16& hi, u16& lo) {
  hi = f2bf(f);
  lo = f2bf(f - bf2f(hi));
}

__device__ __forceinline__ void gload16(const u16* g, const u16* l) {
  __builtin_amdgcn_global_load_lds(
      (const __attribute__((address_space(1))) void*)g,
      (__attribute__((address_space(3))) void*)l, 16, 0, 0);
}

// ================= block reductions =================
__device__ __forceinline__ float block_sum(float v, float* s) {
  #pragma unroll
  for (int o = 32; o > 0; o >>= 1) v += __shfl_down(v, o, 64);
  int w = threadIdx.x >> 6, lane = threadIdx.x & 63;
  __syncthreads();
  if (lane == 0) s[w] = v;
  __syncthreads();
  float r = s[0];
  for (int i = 1; i < 4; ++i) r += s[i];
  return r;
}
__device__ __forceinline__ float block_max(float v, float* s) {
  #pragma unroll
  for (int o = 32; o > 0; o >>= 1) v = fmaxf(v, __shfl_down(v, o, 64));
  int w = threadIdx.x >> 6, lane = threadIdx.x & 63;
  __syncthreads();
  if (lane == 0) s[w] = v;
  __syncthreads();
  float r = s[0];
  for (int i = 1; i < 4; ++i) r = fmaxf(r, s[i]);
  return r;
}

// ================= bf16 MFMA GEMM, 2-phase double-buffered K-loop (128x128 tile) =================
// direct: mode 0: C(f32)=alpha*A@B^T(+Cadd)(+causal); mode 1: Cb=silu(Cadd f32)*(alpha*acc);
//         mode 2: Cb=bf16(alpha*acc); mode 3: Cb=silu(CaddB bf16)*(alpha*acc)
// split-K (pbuf!=null): pbuf[(z*stot+soff+s)][M][ldc] = A@B^T over K-segment s
// gidx: per-row token gather for A; gcnt: per-z valid M (early exit)
// kcap: if 1, clamp kend to (T-aligned segment base)+bm+128 (causal PV; tail of A is zeros)
__global__ __launch_bounds__(256) void gemm_bf16(
    const u16* __restrict__ A, long asz, int lda,
    const u16* __restrict__ B, long bsz, int ldb,
    float* __restrict__ C, u16* __restrict__ Cb, long csz, int ldc,
    const float* __restrict__ Cadd, const u16* __restrict__ CaddB, int ldcadd,
    int K, float alpha, int causal, int mode,
    float* __restrict__ pbuf, int ksplit, int stot, int soff,
    const int* __restrict__ gidx, const int* __restrict__ gcnt, int kcap) {
  const int bm = blockIdx.y << 7, bn = blockIdx.x << 7;
  const int zz = blockIdx.z;
  const int z = (ksplit > 1) ? (zz / ksplit) : zz;
  const int s = (ksplit > 1) ? (zz % ksplit) : 0;
  if (gcnt && bm >= gcnt[z]) return;
  A += (long)z * asz; B += (long)z * bsz;
  if (C) C += (long)z * csz;
  if (Cb) Cb += (long)z * csz;
  if (Cadd && !pbuf) Cadd += (long)z * csz;
  if (CaddB) CaddB += (long)z * csz;
  const int tid = threadIdx.x, lane = tid & 63, wid = tid >> 6;

  if (causal && bn >= bm + 128) return;  // softmax masks by index; no writes needed

  __shared__ alignas(16) u16 As[2][128 * 32];
  __shared__ alignas(16) u16 Bs[2][128 * 32];

  const int wr = wid >> 1, wc = wid & 1;
  f32x4 acc[4][4];
  #pragma unroll
  for (int m = 0; m < 4; ++m)
    #pragma unroll
    for (int n = 0; n < 4; ++n) acc[m][n] = f32x4{0.f, 0.f, 0.f, 0.f};

  const int srow = (wid << 5) + (lane >> 2);
  const int scol = (lane & 3) << 3;
  const int arow = (wr << 6) + (lane & 15);
  const int brow = (wc << 6) + (lane & 15);
  const int koff = (lane >> 4) << 3;

  // A-row gather indices (loop-invariant)
  long ga0, ga1;
  {
    if (gidx) {
      const int* tk = gidx + (long)z * T_TOK;
      ga0 = (long)tk[bm + srow]; ga1 = (long)tk[bm + srow + 16];
    } else {
      ga0 = (long)(bm + srow); ga1 = (long)(bm + srow + 16);
    }
  }

  const int kseg = K / ksplit;
  const int kbeg = s * kseg;
  int kend = kbeg + kseg;
  if (kcap) {
    int segbase = (kbeg / T_TOK) * T_TOK;       // ph vs pl segment origin
    int cap = segbase + bm + 128;               // cols beyond are exact zeros in P2
    if (kend > cap) kend = cap;
  }
  int nIter = (kend - kbeg) >> 5;
  if (nIter < 0) nIter = 0;

  #define STAGE_TILE(BUF, KK)                                                 \
    {                                                                         \
      u16* asp = &As[(BUF)][(wid << 10)];                                     \
      u16* bsp = &Bs[(BUF)][(wid << 10)];                                     \
      gload16(A + ga0 * lda + (KK) + scol, asp);                              \
      gload16(A + ga1 * lda + (KK) + scol, asp + 512);                        \
      gload16(B + (long)(bn + srow) * ldb + (KK) + scol, bsp);                \
      gload16(B + (long)(bn + srow + 16) * ldb + (KK) + scol, bsp + 512);     \
    }

  if (nIter > 0) {
    STAGE_TILE(0, kbeg);
    __syncthreads();

    int cur = 0;
    for (int it = 0; it < nIter; ++it) {
      int k0 = kbeg + (it << 5);
      if (it + 1 < nIter) STAGE_TILE(cur ^ 1, k0 + 32);
      bf16x8 a[4], b[4];
      #pragma unroll
      for (int m = 0; m < 4; ++m) a[m] = *(const bf16x8*)&As[cur][((arow + (m << 4)) << 5) + koff];
      #pragma unroll
      for (int n = 0; n < 4; ++n) b[n] = *(const bf16x8*)&Bs[cur][((brow + (n << 4)) << 5) + koff];
      #pragma unroll
      for (int m = 0; m < 4; ++m)
        #pragma unroll
        for (int n = 0; n < 4; ++n)
          acc[m][n] = __builtin_amdgcn_mfma_f32_16x16x32_bf16(a[m], b[n], acc[m][n], 0, 0, 0);
      __syncthreads();
      cur ^= 1;
    }
  }
  #undef STAGE_TILE

  const int rbase = bm + (wr << 6) + ((lane >> 4) << 2);
  const int cbase = bn + (wc << 6) + (lane & 15);

  if (pbuf) {
    long pstride = (long)(gridDim.y << 7) * ldc;
    float* pp = pbuf + ((long)z * stot + soff + s) * pstride;
    #pragma unroll
    for (int m = 0; m < 4; ++m)
      #pragma unroll
      for (int j = 0; j < 4; ++j) {
        int r = rbase + (m << 4) + j;
        #pragma unroll
        for (int n = 0; n < 4; ++n) {
          int cc = cbase + (n << 4);
          pp[(long)r * ldc + cc] = acc[m][n][j];
        }
      }
    return;
  }

  #pragma unroll
  for (int m = 0; m < 4; ++m) {
    #pragma unroll
    for (int j = 0; j < 4; ++j) {
      int r = rbase + (m << 4) + j;
      #pragma unroll
      for (int n = 0; n < 4; ++n) {
        int cc = cbase + (n << 4);
        float v = acc[m][n][j] * alpha;
        if (mode == 0) {
          if (Cadd) v += Cadd[(long)r * ldcadd + cc];
          if (causal && cc > r) v = NEG_BIG;
          C[(long)r * ldc + cc] = v;
        } else if (mode == 1) {
          float gg = Cadd[(long)r * ldcadd + cc];
          float sgv = gg / (1.f + expf(-gg));
          Cb[(long)r * ldc + cc] = f2bf(sgv * v);
        } else if (mode == 2) {
          Cb[(long)r * ldc + cc] = f2bf(v);
        } else {
          float gg = bf2f(CaddB[(long)r * ldcadd + cc]);
          float sgv = gg / (1.f + expf(-gg));
          Cb[(long)r * ldc + cc] = f2bf(sgv * v);
        }
      }
    }
  }
}

// ================= 64x64-tile bf16 MFMA GEMM (high occupancy; MoE GEMMs) =================
// Cb = bf16(A@B^T); gather + cnt guard. Grid: x = M-blocks (consecutive blocks share B panel),
// y = N-blocks, z = slice. 4 waves, 16KB LDS, 2-phase dbuf.
__global__ __launch_bounds__(256) void gemm64(
    const u16* __restrict__ A, long asz, int lda,
    const u16* __restrict__ B, long bsz, int ldb,
    u16* __restrict__ Cb, long csz, int ldc, int K,
    const int* __restrict__ gidx, const int* __restrict__ gcnt) {
  const int bm = blockIdx.x << 6, bn = blockIdx.y << 6;
  const int z = blockIdx.z;
  if (gcnt && bm >= gcnt[z]) return;
  A += (long)z * asz; B += (long)z * bsz; Cb += (long)z * csz;
  const int tid = threadIdx.x, lane = tid & 63, wid = tid >> 6;

  __shared__ alignas(16) u16 As[2][64 * 32];
  __shared__ alignas(16) u16 Bs[2][64 * 32];

  f32x4 acc[4];
  #pragma unroll
  for (int n = 0; n < 4; ++n) acc[n] = f32x4{0.f, 0.f, 0.f, 0.f};

  const int srow = tid >> 2;          // 0..63
  const int scol = (tid & 3) << 3;
  long ga;
  if (gidx) ga = (long)gidx[(long)z * T_TOK + bm + srow];
  else ga = (long)(bm + srow);

  const int arow = (wid << 4) + (lane & 15);   // rows this wave computes
  const int koff = (lane >> 4) << 3;
  const int nIter = K >> 5;

  // each wave writes 64 lanes x 16B = 1024B = 512 u16 -> stride wid<<9
  #define STAGE64(BUF, KK)                                                    \
    {                                                                         \
      gload16(A + ga * lda + (KK) + scol, &As[(BUF)][(wid << 9)]);            \
      gload16(B + (long)(bn + srow) * ldb + (KK) + scol, &Bs[(BUF)][(wid << 9)]); \
    }

  STAGE64(0, 0);
  __syncthreads();

  int cur = 0;
  for (int it = 0; it < nIter; ++it) {
    if (it + 1 < nIter) STAGE64(cur ^ 1, (it + 1) << 5);
    bf16x8 a, b[4];
    a = *(const bf16x8*)&As[cur][(arow << 5) + koff];
    #pragma unroll
    for (int n = 0; n < 4; ++n)
      b[n] = *(const bf16x8*)&Bs[cur][(((n << 4) + (lane & 15)) << 5) + koff];
    #pragma unroll
    for (int n = 0; n < 4; ++n)
      acc[n] = __builtin_amdgcn_mfma_f32_16x16x32_bf16(a, b[n], acc[n], 0, 0, 0);
    __syncthreads();
    cur ^= 1;
  }
  #undef STAGE64

  const int rbase = bm + (wid << 4) + ((lane >> 4) << 2);
  const int cbase = bn + (lane & 15);
  #pragma unroll
  for (int j = 0; j < 4; ++j) {
    int r = rbase + j;
    #pragma unroll
    for (int n = 0; n < 4; ++n) {
      int cc = cbase + (n << 4);
      Cb[(long)r * ldc + cc] = f2bf(acc[n][j]);
    }
  }
}

// ================= split-K reduce + epilogue =================
// mode 0: C(f32)=alpha*sum+Cadd; mode 1: Cb=silu(Cadd)*alpha*sum (bf16)
// mode 2: Cb = split3 A-layout bf16: row r stride 3*ldc; [hi | lo | hi] at +0/+ldc/+2*ldc
__global__ __launch_bounds__(256) void reduce_sk(
    const float* __restrict__ pbuf, long pstride, int S,
    float* __restrict__ C, u16* __restrict__ Cb, long csz, int ldc, int Nc,
    const float* __restrict__ Cadd, long caddsz, int ldcadd,
    float alpha, int mode) {
  const int z = blockIdx.y;
  const float* pz = pbuf + (long)z * S * pstride;
  long idx = ((long)blockIdx.x * 256 + threadIdx.x) * 8;
  long r = idx / Nc; int c = (int)(idx - r * Nc);
  float a[8] = {0.f, 0.f, 0.f, 0.f, 0.f, 0.f, 0.f, 0.f};
  for (int s = 0; s < S; ++s) {
    const float* pp = pz + (long)s * pstride + idx;
    float4 x = *(const float4*)pp;
    float4 y = *(const float4*)(pp + 4);
    a[0] += x.x; a[1] += x.y; a[2] += x.z; a[3] += x.w;
    a[4] += y.x; a[5] += y.y; a[6] += y.z; a[7] += y.w;
  }
  if (mode == 0) {
    long ob = (long)z * csz + r * ldc + c;
    #pragma unroll
    for (int k = 0; k < 8; ++k) {
      float v = a[k] * alpha;
      if (Cadd) v += Cadd[(long)z * caddsz + r * ldcadd + c + k];
      C[ob + k] = v;
    }
  } else if (mode == 1) {
    long ob = (long)z * csz + r * ldc + c;
    u16x8 o;
    #pragma unroll
    for (int k = 0; k < 8; ++k) {
      float gg = Cadd[(long)z * caddsz + r * ldcadd + c + k];
      float sgv = gg / (1.f + expf(-gg));
      o[k] = f2bf(sgv * a[k] * alpha);
    }
    *(u16x8*)&Cb[ob] = o;
  } else {
    long base = r * (3L * ldc) + (long)z * csz + c;
    u16x8 hv, lv;
    #pragma unroll
    for (int k = 0; k < 8; ++k) {
      u16 hi, lo; split2(a[k] * alpha, hi, lo);
      hv[k] = hi; lv[k] = lo;
    }
    *(u16x8*)&Cb[base] = hv;
    *(u16x8*)&Cb[base + ldc] = lv;
    *(u16x8*)&Cb[base + 2 * ldc] = hv;
  }
}

// ================= transpose f32 [K][N] -> plain bf16 [Npad][K] =================
__global__ __launch_bounds__(256) void transpose_f32_bf16(
    const float* __restrict__ src, long sbs, int ld_src, int Cvalid,
    u16* __restrict__ dst, long dbs, int ld_dst) {
  __shared__ float tile[64][65];
  src += (long)blockIdx.z * sbs; dst += (long)blockIdx.z * dbs;
  const int c0 = blockIdx.x << 6, r0 = blockIdx.y << 6;
  const int tid = threadIdx.x;
  const int tc = (tid & 15) << 2, tr0 = tid >> 4;
  const bool valid = c0 < Cvalid;
  #pragma unroll
  for (int i = 0; i < 4; ++i) {
    int r = tr0 + (i << 4);
    float4 v;
    if (valid) v = *(const float4*)&src[(long)(r0 + r) * ld_src + c0 + tc];
    else { v.x = 0.f; v.y = 0.f; v.z = 0.f; v.w = 0.f; }
    tile[r][tc] = v.x; tile[r][tc + 1] = v.y; tile[r][tc + 2] = v.z; tile[r][tc + 3] = v.w;
  }
  __syncthreads();
  const int oc = tid >> 2, seg = tid & 3;
  u16x8 o0, o1;
  #pragma unroll
  for (int k = 0; k < 8; ++k) o0[k] = f2bf(tile[(seg << 4) + k][oc]);
  #pragma unroll
  for (int k = 0; k < 8; ++k) o1[k] = f2bf(tile[(seg << 4) + 8 + k][oc]);
  u16* dp = &dst[(long)(c0 + oc) * ld_dst + r0 + (seg << 4)];
  *(u16x8*)dp = o0;
  *(u16x8*)(dp + 8) = o1;
}

// ================= transpose f32 [K][N] -> split3 B-side bf16 [Npad][3K] = [hi|hi|lo] =================
__global__ __launch_bounds__(256) void transpose_split3(
    const float* __restrict__ src, long sbs, int ld_src, int Cvalid,
    u16* __restrict__ dst, long dbs, int Kp) {
  __shared__ float tile[64][65];
  src += (long)blockIdx.z * sbs; dst += (long)blockIdx.z * dbs;
  const int c0 = blockIdx.x << 6, r0 = blockIdx.y << 6;
  const int tid = threadIdx.x;
  const int tc = (tid & 15) << 2, tr0 = tid >> 4;
  const bool valid = c0 < Cvalid;
  #pragma unroll
  for (int i = 0; i < 4; ++i) {
    int r = tr0 + (i << 4);
    float4 v;
    if (valid) v = *(const float4*)&src[(long)(r0 + r) * ld_src + c0 + tc];
    else { v.x = 0.f; v.y = 0.f; v.z = 0.f; v.w = 0.f; }
    tile[r][tc] = v.x; tile[r][tc + 1] = v.y; tile[r][tc + 2] = v.z; tile[r][tc + 3] = v.w;
  }
  __syncthreads();
  const int oc = tid >> 2, seg = tid & 3;
  u16x8 h0, h1, l0, l1;
  #pragma unroll
  for (int k = 0; k < 8; ++k) {
    u16 hi, lo; split2(tile[(seg << 4) + k][oc], hi, lo);
    h0[k] = hi; l0[k] = lo;
  }
  #pragma unroll
  for (int k = 0; k < 8; ++k) {
    u16 hi, lo; split2(tile[(seg << 4) + 8 + k][oc], hi, lo);
    h1[k] = hi; l1[k] = lo;
  }
  const int ldd = 3 * Kp;
  u16* dp = &dst[(long)(c0 + oc) * ldd + r0 + (seg << 4)];
  *(u16x8*)dp = h0;            *(u16x8*)(dp + 8) = h1;
  *(u16x8*)(dp + Kp) = h0;     *(u16x8*)(dp + Kp + 8) = h1;
  *(u16x8*)(dp + 2 * Kp) = l0; *(u16x8*)(dp + 2 * Kp + 8) = l1;
}

// ================= add + RMS -> resid1(f32), h3(split3 A-side) =================
__global__ __launch_bounds__(256) void add_rms_kernel(
    const float* __restrict__ hs, const float* __restrict__ res,
    const float* __restrict__ w, float* __restrict__ resid1, u16* __restrict__ h3) {
  __shared__ float sbuf[4];
  int t = blockIdx.x;
  float v[8]; float ss = 0.f;
  #pragma unroll
  for (int i = 0; i < 8; ++i) {
    int j = threadIdx.x + (i << 8);
    float x = hs[(long)t * HID + j] + res[(long)t * HID + j];
    v[i] = x; resid1[(long)t * HID + j] = x; ss += x * x;
  }
  ss = block_sum(ss, sbuf);
  float sc = rsqrtf(ss / (float)HID + EPSF);
  u16* base = h3 + (long)t * (3 * HID);
  #pragma unroll
  for (int i = 0; i < 8; ++i) {
    int j = threadIdx.x + (i << 8);
    u16 hi, lo; split2(v[i] * sc * w[j], hi, lo);
    base[j] = hi; base[HID + j] = lo; base[2 * HID + j] = hi;
  }
}

// ================= row RMS -> split3 or plain bf16 (+f32) =================
template <int NW, bool SPLIT, bool WF32>
__global__ __launch_bounds__(256) void rms_rows_kernel(
    const float* __restrict__ in, int ldin, const float* __restrict__ w,
    u16* __restrict__ outb, float* __restrict__ outf) {
  __shared__ float sbuf[4];
  int t = blockIdx.x;
  const int W = NW * 256;
  float v[NW]; float ss = 0.f;
  #pragma unroll
  for (int i = 0; i < NW; ++i) {
    int j = threadIdx.x + (i << 8);
    float x = in[(long)t * ldin + j];
    v[i] = x; ss += x * x;
  }
  ss = block_sum(ss, sbuf);
  float sc = rsqrtf(ss / (float)W + EPSF);
  #pragma unroll
  for (int i = 0; i < NW; ++i) {
    int j = threadIdx.x + (i << 8);
    float y = v[i] * sc * w[j];
    if (SPLIT) {
      u16 hi, lo; split2(y, hi, lo);
      u16* base = outb + (long)t * (3 * W);
      base[j] = hi; base[W + j] = lo; base[2 * W + j] = hi;
    } else {
      outb[(long)t * W + j] = f2bf(y);
    }
    if (WF32) outf[(long)t * W + j] = y;
  }
}

// ================= RoPE (f32, in place on qbuf; qkv k_pe -> kpe) =================
__global__ __launch_bounds__(256) void rope_kernel(
    const int* __restrict__ pos, float* __restrict__ q,
    const float* __restrict__ qkv, float* __restrict__ kpe) {
  int t = blockIdx.x;
  float fp = (float)pos[t];
  for (int item = threadIdx.x; item < 544; item += 256) {
    int i = item & 31;
    float inv = expf(-((float)i * (2.f / 64.f)) * 9.210340371976184f);
    float ang = fp * inv;
    float c = cosf(ang), s = sinf(ang);
    if (item < 512) {
      int hh = item >> 5;
      long base = (long)t * (HEADS * QD) + hh * QD + NOPE;
      float x1 = q[base + i], x2 = q[base + 32 + i];
      q[base + i] = x1 * c - x2 * s;
      q[base + 32 + i] = x2 * c + x1 * s;
    } else {
      long base = (long)t * QKV_LD + (Q_LORA + KV_LORA);
      float x1 = qkv[base + i], x2 = qkv[base + 32 + i];
      kpe[(long)t * 64 + i] = x1 * c - x2 * s;
      kpe[(long)t * 64 + 32 + i] = x2 * c + x1 * s;
    }
  }
}

// ================= q3 per head: A-side [16][T][3*192] = [hi|lo|hi] =================
__global__ __launch_bounds__(192) void build_q3_kernel(
    const float* __restrict__ qbuf, u16* __restrict__ q3) {
  int t = blockIdx.x, h = blockIdx.y, d = threadIdx.x;
  float x = qbuf[(long)t * (HEADS * QD) + h * QD + d];
  u16 hi, lo; split2(x, hi, lo);
  u16* base = q3 + ((long)h * T_TOK + t) * (3 * QD);
  base[d] = hi; base[QD + d] = lo; base[2 * QD + d] = hi;
}

// ================= kmat3 per head: B-side [16][T][3*192] = [hi|hi|lo] =================
__global__ __launch_bounds__(192) void build_kmat3_kernel(
    const float* __restrict__ kv, const float* __restrict__ kpe,
    u16* __restrict__ kmat3) {
  int t = blockIdx.x, h = blockIdx.y, d = threadIdx.x;
  float v = (d < NOPE) ? kv[(long)t * (HEADS * KVD) + h * KVD + d]
                       : kpe[(long)t * 64 + (d - NOPE)];
  u16 hi, lo; split2(v, hi, lo);
  u16* base = kmat3 + ((long)h * T_TOK + t) * (3 * QD);
  base[d] = hi; base[QD + d] = hi; base[2 * QD + d] = lo;
}

// ================= masked softmax row -> P2 [row][2*1024] = [hi|lo] (prefix-only loads) =================
__global__ __launch_bounds__(256) void softmax_kernel(
    const float* __restrict__ S, u16* __restrict__ P2) {
  __shared__ float sbuf[4];
  long row = blockIdx.x;
  int r = (int)(row & (T_TOK - 1));
  const float* p = S + row * T_TOK;
  int c0 = threadIdx.x << 2;
  float4 v;
  if (c0 <= r) {
    v = ((const float4*)p)[threadIdx.x];
    if (c0 + 1 > r) v.y = NEG_BIG;
    if (c0 + 2 > r) v.z = NEG_BIG;
    if (c0 + 3 > r) v.w = NEG_BIG;
  } else {
    v.x = NEG_BIG; v.y = NEG_BIG; v.z = NEG_BIG; v.w = NEG_BIG;
  }
  float m = fmaxf(fmaxf(v.x, v.y), fmaxf(v.z, v.w));
  m = block_max(m, sbuf);
  v.x = expf(v.x - m); v.y = expf(v.y - m); v.z = expf(v.z - m); v.w = expf(v.w - m);
  float s = v.x + v.y + v.z + v.w;
  s = block_sum(s, sbuf);
  float inv = 1.f / s;
  u16x4 hv, lv;
  u16 hi, lo;
  split2(v.x * inv, hi, lo); hv[0] = hi; lv[0] = lo;
  split2(v.y * inv, hi, lo); hv[1] = hi; lv[1] = lo;
  split2(v.z * inv, hi, lo); hv[2] = hi; lv[2] = lo;
  split2(v.w * inv, hi, lo); hv[3] = hi; lv[3] = lo;
  u16* base = P2 + row * (2 * T_TOK) + (threadIdx.x << 2);
  *(u16x4*)base = hv;
  *(u16x4*)(base + T_TOK) = lv;
}

// ================= gate + top-2 -> ti[t][2], tw[t][2] =================
__global__ __launch_bounds__(256) void gate_topk_kernel(
    const float* __restrict__ h2, const float* __restrict__ gw,
    int* __restrict__ ti, float* __restrict__ tw) {
  __shared__ float sbuf[4];
  __shared__ float lg[N_EXP];
  int t = blockIdx.x;
  float p[N_EXP] = {0.f, 0.f, 0.f, 0.f, 0.f, 0.f, 0.f, 0.f};
  for (int j = threadIdx.x; j < HID; j += 256) {
    float x = h2[(long)t * HID + j];
    const float* gr = gw + (long)j * N_EXP;
    #pragma unroll
    for (int e = 0; e < N_EXP; ++e) p[e] += x * gr[e];
  }
  #pragma unroll
  for (int e = 0; e < N_EXP; ++e) {
    float s = block_sum(p[e], sbuf);
    if (threadIdx.x == 0) lg[e] = s;
  }
  __syncthreads();
  if (threadIdx.x == 0) {
    float m = lg[0];
    for (int e = 1; e < N_EXP; ++e) m = fmaxf(m, lg[e]);
    float pe[N_EXP]; float s = 0.f;
    for (int e = 0; e < N_EXP; ++e) { pe[e] = expf(lg[e] - m); s += pe[e]; }
    for (int e = 0; e < N_EXP; ++e) pe[e] /= s;
    int i0 = 0;
    for (int e = 1; e < N_EXP; ++e) if (pe[e] > pe[i0]) i0 = e;
    int i1 = -1;
    for (int e = 0; e < N_EXP; ++e) if (e != i0 && (i1 < 0 || pe[e] > pe[i1])) i1 = e;
    float ssum = pe[i0] + pe[i1];
    ti[2 * t] = i0; ti[2 * t + 1] = i1;
    tw[2 * t] = pe[i0] / ssum; tw[2 * t + 1] = pe[i1] / ssum;
  }
}

// ================= routing lists for 20 z-slices (z and z+10 identical): tokidx20, cnt20, pos =================
__global__ __launch_bounds__(64) void route_build_kernel(
    const int* __restrict__ ti, int* __restrict__ tokidx,
    int* __restrict__ pos, int* __restrict__ cnt) {
  int e = blockIdx.x;            // 0..19
  int le = (e < 10) ? e : e - 10;
  int lane = threadIdx.x;
  if (le >= N_EXP) {  // shared virtual experts: identity
    for (int p = lane; p < T_TOK; p += 64) tokidx[(long)e * T_TOK + p] = p;
    if (lane == 0) cnt[e] = T_TOK;
    return;
  }
  int c = 0;
  for (int base = 0; base < T_TOK; base += 64) {
    int t = base + lane;
    int e0 = ti[2 * t], e1 = ti[2 * t + 1];
    bool match = (e0 == le) || (e1 == le);
    unsigned long long mask = __ballot(match);
    int pref = __popcll(mask & ((1ull << lane) - 1ull));
    if (match) {
      int p = c + pref;
      tokidx[(long)e * T_TOK + p] = t;
      if (e < 10) pos[2 * t + ((e0 == le) ? 0 : 1)] = p;
    }
    c += __popcll(mask);
  }
  for (int p = c + lane; p < T_TOK; p += 64) tokidx[(long)e * T_TOK + p] = 0;
  if (lane == 0) cnt[e] = c;
}

// ================= silu over split gate|up z-slices: gact[e][r][i] = silu(gug[e][r][i]) * gug[e+10][r][i] =================
__global__ __launch_bounds__(256) void silu_mul_moe_kernel(
    const u16* __restrict__ gug, const int* __restrict__ cnt,
    u16* __restrict__ gact) {
  int r = blockIdx.x, e = blockIdx.y;
  int padded = (cnt[e] + 63) & ~63;
  if (r >= padded) return;
  int j = threadIdx.x << 3;
  if (j >= MOE_I) return;
  u16x8 gv = *(const u16x8*)&gug[((long)e * T_TOK + r) * MOE_I + j];
  u16x8 uv = *(const u16x8*)&gug[(((long)e + 10) * T_TOK + r) * MOE_I + j];
  u16x8 o;
  #pragma unroll
  for (int k = 0; k < 8; ++k) {
    float g = bf2f(gv[k]);
    o[k] = f2bf(g / (1.f + expf(-g)) * bf2f(uv[k]));
  }
  *(u16x8*)&gact[((long)e * T_TOK + r) * MOE_I + j] = o;
}

// ================= out0[t] = tw0*y[e0][p0] + tw1*y[e1][p1] + y[8][t] + y[9][t] =================
__global__ __launch_bounds__(256) void combine_out_kernel(
    const u16* __restrict__ y, const int* __restrict__ ti,
    const float* __restrict__ tw, const int* __restrict__ pos,
    float* __restrict__ out0) {
  int t = blockIdx.x;
  int j = threadIdx.x << 3;
  int e0 = ti[2 * t], e1 = ti[2 * t + 1];
  int p0 = pos[2 * t], p1 = pos[2 * t + 1];
  float w0 = tw[2 * t], w1 = tw[2 * t + 1];
  u16x8 a = *(const u16x8*)&y[((long)e0 * T_TOK + p0) * HID + j];
  u16x8 b = *(const u16x8*)&y[((long)e1 * T_TOK + p1) * HID + j];
  u16x8 c = *(const u16x8*)&y[((long)8 * T_TOK + t) * HID + j];
  u16x8 d = *(const u16x8*)&y[((long)9 * T_TOK + t) * HID + j];
  float* rp = out0 + (long)t * HID + j;
  #pragma unroll
  for (int k = 0; k < 8; ++k)
    rp[k] = w0 * bf2f(a[k]) + w1 * bf2f(b[k]) + bf2f(c[k]) + bf2f(d[k]);
}

// ================= launcher =================
extern "C" void kernel_launch(void* const* d_in, const int* in_sizes, int n_in,
                              void* d_out, int out_size, void* d_ws, size_t ws_size,
                              hipStream_t stream) {
  (void)in_sizes; (void)n_in; (void)out_size; (void)ws_size;
  const int*   positions = (const int*)d_in[0];
  const float* hs        = (const float*)d_in[1];
  const float* res       = (const float*)d_in[2];
  const float* w_in_ln   = (const float*)d_in[3];
  const float* w_post_ln = (const float*)d_in[4];
  const float* w_q_ln    = (const float*)d_in[5];
  const float* w_kv_ln   = (const float*)d_in[6];
  const float* w_qkv_a   = (const float*)d_in[7];
  const float* w_q_b     = (const float*)d_in[8];
  const float* w_kv_b    = (const float*)d_in[9];
  const float* w_o       = (const float*)d_in[10];
  const float* gate_w    = (const float*)d_in[11];
  const float* we_gate   = (const float*)d_in[12];
  const float* we_up     = (const float*)d_in[13];
  const float* we_down   = (const float*)d_in[14];
  const float* ws_gate   = (const float*)d_in[15];
  const float* ws_up     = (const float*)d_in[16];
  const float* ws_dn     = (const float*)d_in[17];

  float* out0   = (float*)d_out;
  float* resid2 = out0 + (long)T_TOK * HID;

  char* Wb = (char*)d_ws;
  size_t off = 0;
  #define CARVE(name, type, bytes) type* name = (type*)(Wb + off); off += (((size_t)(bytes) + 255) & ~(size_t)255)

  // ---- W1: persistent split3 attention weights ----
  CARVE(wqkvaT3, u16, (size_t)QKV_LD * 3 * HID * 2);
  CARVE(wqbT3,   u16, (size_t)(HEADS * QD) * 3 * Q_LORA * 2);
  CARVE(wkvbT3,  u16, (size_t)(HEADS * KVD) * 3 * KV_LORA * 2);
  CARVE(woT3,    u16, (size_t)HID * 3 * HID * 2);

  size_t pool = off;
  // ---- phase A scratch ----
  CARVE(resid1, float, (size_t)T_TOK * HID * 4);
  CARVE(h3,     u16,   (size_t)T_TOK * 3 * HID * 2);
  CARVE(qkv,    float, (size_t)T_TOK * QKV_LD * 4);
  CARVE(qc3,    u16,   (size_t)T_TOK * 3 * Q_LORA * 2);
  CARVE(kvc3,   u16,   (size_t)T_TOK * 3 * KV_LORA * 2);
  CARVE(qbuf,   float, (size_t)T_TOK * HEADS * QD * 4);
  CARVE(q3,     u16,   (size_t)HEADS * T_TOK * 3 * QD * 2);
  CARVE(kvbuf,  float, (size_t)T_TOK * HEADS * KVD * 4);
  CARVE(kpe,    float, (size_t)T_TOK * 64 * 4);
  CARVE(kmat3,  u16,   (size_t)HEADS * T_TOK * 3 * QD * 2);
  CARVE(vt3,    u16,   (size_t)HEADS * VD * 3 * T_TOK * 2);
  CARVE(scores, float, (size_t)HEADS * T_TOK * T_TOK * 4);   // doubles as phase-A split-K pbuf
  CARVE(P2,     u16,   (size_t)HEADS * T_TOK * 2 * T_TOK * 2);
  CARVE(attn3,  u16,   (size_t)T_TOK * 3 * HID * 2);
  size_t endA = off;
  float* pbufA = scores;

  // ---- phase B (aliases phase A; written only after step 11) ----
  off = pool;
  CARVE(wegu20, u16, (size_t)20 * MOE_I * HID * 2);   // [0..9]=gate (8 routed + 2 shared), [10..19]=up
  CARVE(wedT10, u16, (size_t)10 * HID * MOE_I * 2);
  CARVE(h2,     float, (size_t)T_TOK * HID * 4);
  CARVE(h2_b,   u16,   (size_t)T_TOK * HID * 2);
  CARVE(ti,     int,   (size_t)T_TOK * 2 * 4);
  CARVE(tw,     float, (size_t)T_TOK * 2 * 4);
  CARVE(pos,    int,   (size_t)T_TOK * 2 * 4);
  CARVE(tokidx20, int, (size_t)20 * T_TOK * 4);
  CARVE(cnt20,  int,   128);
  CARVE(gug20,  u16,   (size_t)20 * T_TOK * MOE_I * 2);
  CARVE(gact,   u16,   (size_t)10 * T_TOK * MOE_I * 2);
  CARVE(ycomp,  u16,   (size_t)10 * T_TOK * HID * 2);
  if (off < endA) off = endA;
  #undef CARVE

  u16* wegT10 = wegu20;                                  // gate slices
  u16* weuT10 = wegu20 + (size_t)10 * MOE_I * HID;       // up slices

  const float* nullf = nullptr;
  float* nullC = nullptr;
  u16* nullB = nullptr;
  const u16* nullBB = nullptr;
  const int* nullI = nullptr;

  // ---- 0. attention weight transposes (split3) ----
  hipLaunchKernelGGL(transpose_split3, dim3(QKV_LD / 64, HID / 64, 1), dim3(256), 0, stream,
                     w_qkv_a, 0L, QKV_N, QKV_N, wqkvaT3, 0L, HID);
  hipLaunchKernelGGL(transpose_split3, dim3(HEADS * QD / 64, Q_LORA / 64, 1), dim3(256), 0, stream,
                     w_q_b, 0L, HEADS * QD, HEADS * QD, wqbT3, 0L, Q_LORA);
  hipLaunchKernelGGL(transpose_split3, dim3(HEADS * KVD / 64, KV_LORA / 64, 1), dim3(256), 0, stream,
                     w_kv_b, 0L, HEADS * KVD, HEADS * KVD, wkvbT3, 0L, KV_LORA);
  hipLaunchKernelGGL(transpose_split3, dim3(HID / 64, HID / 64, 1), dim3(256), 0, stream,
                     w_o, 0L, HID, HID, woT3, 0L, HID);

  // ---- 1. resid1 = hs+res; h3 = split3(rms) ----
  hipLaunchKernelGGL(add_rms_kernel, dim3(T_TOK), dim3(256), 0, stream,
                     hs, res, w_in_ln, resid1, h3);
  // ---- 2. qkv = h @ w_qkv_a (split3 K'=6144, split-K 4) ----
  hipLaunchKernelGGL(gemm_bf16, dim3(QKV_LD / 128, T_TOK / 128, 4), dim3(256), 0, stream,
                     h3, 0L, 3 * HID, wqkvaT3, 0L, 3 * HID,
                     nullC, nullB, 0L, QKV_LD, nullf, nullBB, 0, 3 * HID, 1.f, 0, 0,
                     pbufA, 4, 4, 0, nullI, nullI, 0);
  hipLaunchKernelGGL(reduce_sk, dim3(T_TOK * QKV_LD / 2048, 1), dim3(256), 0, stream,
                     pbufA, (long)T_TOK * QKV_LD, 4,
                     qkv, nullB, 0L, QKV_LD, QKV_LD, nullf, 0L, 0, 1.f, 0);
  // ---- 3. q_c, kv_c RMS -> split3 ----
  hipLaunchKernelGGL((rms_rows_kernel<6, true, false>), dim3(T_TOK), dim3(256), 0, stream,
                     qkv, QKV_LD, w_q_ln, qc3, (float*)nullptr);
  hipLaunchKernelGGL((rms_rows_kernel<2, true, false>), dim3(T_TOK), dim3(256), 0, stream,
                     qkv + Q_LORA, QKV_LD, w_kv_ln, kvc3, (float*)nullptr);
  // ---- 4. q = q_c @ w_q_b (split3 K'=4608, split-K 4) ----
  hipLaunchKernelGGL(gemm_bf16, dim3(HEADS * QD / 128, T_TOK / 128, 4), dim3(256), 0, stream,
                     qc3, 0L, 3 * Q_LORA, wqbT3, 0L, 3 * Q_LORA,
                     nullC, nullB, 0L, HEADS * QD, nullf, nullBB, 0, 3 * Q_LORA, 1.f, 0, 0,
                     pbufA, 4, 4, 0, nullI, nullI, 0);
  hipLaunchKernelGGL(reduce_sk, dim3(T_TOK * HEADS * QD / 2048, 1), dim3(256), 0, stream,
                     pbufA, (long)T_TOK * HEADS * QD, 4,
                     qbuf, nullB, 0L, HEADS * QD, HEADS * QD, nullf, 0L, 0, 1.f, 0);
  // ---- 5. kv = kv_c @ w_kv_b (split3 K'=1536, split-K 4) ----
  hipLaunchKernelGGL(gemm_bf16, dim3(HEADS * KVD / 128, T_TOK / 128, 4), dim3(256), 0, stream,
                     kvc3, 0L, 3 * KV_LORA, wkvbT3, 0L, 3 * KV_LORA,
                     nullC, nullB, 0L, HEADS * KVD, nullf, nullBB, 0, 3 * KV_LORA, 1.f, 0, 0,
                     pbufA, 4, 4, 0, nullI, nullI, 0);
  hipLaunchKernelGGL(reduce_sk, dim3(T_TOK * HEADS * KVD / 2048, 1), dim3(256), 0, stream,
                     pbufA, (long)T_TOK * HEADS * KVD, 4,
                     kvbuf, nullB, 0L, HEADS * KVD, HEADS * KVD, nullf, 0L, 0, 1.f, 0);
  // ---- 6. RoPE ----
  hipLaunchKernelGGL(rope_kernel, dim3(T_TOK), dim3(256), 0, stream,
                     positions, qbuf, qkv, kpe);
  // ---- 7. q3, kmat3, vt3 ----
  hipLaunchKernelGGL(build_q3_kernel, dim3(T_TOK, HEADS), dim3(192), 0, stream, qbuf, q3);
  hipLaunchKernelGGL(build_kmat3_kernel, dim3(T_TOK, HEADS), dim3(192), 0, stream,
                     kvbuf, kpe, kmat3);
  hipLaunchKernelGGL(transpose_split3, dim3(VD / 64, T_TOK / 64, HEADS), dim3(256), 0, stream,
                     kvbuf + NOPE, 256L, HEADS * KVD, VD, vt3, (long)VD * 3 * T_TOK, T_TOK);
  // ---- 8. scores (split3 K'=576, causal; masked tiles skipped) ----
  hipLaunchKernelGGL(gemm_bf16, dim3(T_TOK / 128, T_TOK / 128, HEADS), dim3(256), 0, stream,
                     q3, (long)T_TOK * 3 * QD, 3 * QD,
                     kmat3, (long)T_TOK * 3 * QD, 3 * QD,
                     scores, nullB, (long)T_TOK * T_TOK, T_TOK,
                     nullf, nullBB, 0, 576, 0.07216878364870322f, 1, 0,
                     nullC, 1, 1, 0, nullI, nullI, 0);
  // ---- 9. masked softmax (prefix-only reads) -> P2 [hi|lo] ----
  hipLaunchKernelGGL(softmax_kernel, dim3(HEADS * T_TOK), dim3(256), 0, stream, scores, P2);
  // ---- 10. PV with causal K-clamp: [ph|pl]@[vh|vh] (K=2048, S=4) + ph@vl (K=1024, S=2) ----
  hipLaunchKernelGGL(gemm_bf16, dim3(VD / 128, T_TOK / 128, HEADS * 4), dim3(256), 0, stream,
                     P2, (long)T_TOK * 2 * T_TOK, 2 * T_TOK,
                     vt3, (long)VD * 3 * T_TOK, 3 * T_TOK,
                     nullC, nullB, 0L, VD, nullf, nullBB, 0, 2 * T_TOK, 1.f, 0, 0,
                     pbufA, 4, 6, 0, nullI, nullI, 1);
  hipLaunchKernelGGL(gemm_bf16, dim3(VD / 128, T_TOK / 128, HEADS * 2), dim3(256), 0, stream,
                     P2, (long)T_TOK * 2 * T_TOK, 2 * T_TOK,
                     vt3 + 2 * T_TOK, (long)VD * 3 * T_TOK, 3 * T_TOK,
                     nullC, nullB, 0L, VD, nullf, nullBB, 0, T_TOK, 1.f, 0, 0,
                     pbufA, 2, 6, 4, nullI, nullI, 1);
  // reduce writes attn3 (split3 A-layout) directly: mode 2
  hipLaunchKernelGGL(reduce_sk, dim3(T_TOK * VD / 2048, HEADS), dim3(256), 0, stream,
                     pbufA, (long)T_TOK * VD, 6,
                     nullC, attn3, (long)VD, HID, VD, nullf, 0L, 0, 1.f, 2);
  // ---- 11. resid2 = resid1 + attn @ w_o (split3 K'=6144, split-K 4) ----
  hipLaunchKernelGGL(gemm_bf16, dim3(HID / 128, T_TOK / 128, 4), dim3(256), 0, stream,
                     attn3, 0L, 3 * HID, woT3, 0L, 3 * HID,
                     nullC, nullB, 0L, HID, nullf, nullBB, 0, 3 * HID, 1.f, 0, 0,
                     pbufA, 4, 4, 0, nullI, nullI, 0);
  hipLaunchKernelGGL(reduce_sk, dim3(T_TOK * HID / 2048, 1), dim3(256), 0, stream,
                     pbufA, (long)T_TOK * HID, 4,
                     resid2, nullB, 0L, HID, HID, resid1, 0L, HID, 1.f, 0);

  // ---- phase-B weight transposes: [gate×10 | up×10] + down×10 ----
  hipLaunchKernelGGL(transpose_f32_bf16, dim3(MOE_I / 64, HID / 64, N_EXP), dim3(256), 0, stream,
                     we_gate, (long)HID * MOE_I, MOE_I, MOE_I, wegT10, (long)MOE_I * HID, HID);
  hipLaunchKernelGGL(transpose_f32_bf16, dim3(MOE_I / 64, HID / 64, 2), dim3(256), 0, stream,
                     ws_gate, (long)MOE_I, SH_I, MOE_I,
                     wegT10 + (size_t)8 * MOE_I * HID, (long)MOE_I * HID, HID);
  hipLaunchKernelGGL(transpose_f32_bf16, dim3(MOE_I / 64, HID / 64, N_EXP), dim3(256), 0, stream,
                     we_up, (long)HID * MOE_I, MOE_I, MOE_I, weuT10, (long)MOE_I * HID, HID);
  hipLaunchKernelGGL(transpose_f32_bf16, dim3(MOE_I / 64, HID / 64, 2), dim3(256), 0, stream,
                     ws_up, (long)MOE_I, SH_I, MOE_I,
                     weuT10 + (size_t)8 * MOE_I * HID, (long)MOE_I * HID, HID);
  hipLaunchKernelGGL(transpose_f32_bf16, dim3(HID / 64, MOE_I / 64, N_EXP), dim3(256), 0, stream,
                     we_down, (long)MOE_I * HID, HID, HID, wedT10, (long)HID * MOE_I, MOE_I);
  hipLaunchKernelGGL(transpose_f32_bf16, dim3(HID / 64, MOE_I / 64, 2), dim3(256), 0, stream,
                     ws_dn, (long)MOE_I * HID, HID, HID,
                     wedT10 + (size_t)8 * HID * MOE_I, (long)HID * MOE_I, MOE_I);

  // ---- 12. h2 = rms(resid2) ----
  hipLaunchKernelGGL((rms_rows_kernel<8, false, true>), dim3(T_TOK), dim3(256), 0, stream,
                     resid2, HID, w_post_ln, h2_b, h2);
  // ---- 13. gating + routing lists (20 z-slices) ----
  hipLaunchKernelGGL(gate_topk_kernel, dim3(T_TOK), dim3(256), 0, stream,
                     h2, gate_w, ti, tw);
  hipLaunchKernelGGL(route_build_kernel, dim3(20), dim3(64), 0, stream,
                     ti, tokidx20, pos, cnt20);
  // ---- 14. gate+up: ONE 20-z 64-tile launch (gathered, M-fastest grid) -> gug20; silu -> gact ----
  hipLaunchKernelGGL(gemm64, dim3(T_TOK / 64, MOE_I / 64, 20), dim3(256), 0, stream,
                     h2_b, 0L, HID, wegu20, (long)MOE_I * HID, HID,
                     gug20, (long)T_TOK * MOE_I, MOE_I, HID, tokidx20, cnt20);
  hipLaunchKernelGGL(silu_mul_moe_kernel, dim3(T_TOK, 10), dim3(256), 0, stream,
                     gug20, cnt20, gact);
  // ---- 15. down over compact rows (64-tile, cnt-guarded) -> ycomp ----
  hipLaunchKernelGGL(gemm64, dim3(T_TOK / 64, HID / 64, 10), dim3(256), 0, stream,
                     gact, (long)T_TOK * MOE_I, MOE_I, wedT10, (long)HID * MOE_I, MOE_I,
                     ycomp, (long)T_TOK * HID, HID, MOE_I, nullI, cnt20);
  // ---- 16. combine: out0 = tw0*y[e0][p0] + tw1*y[e1][p1] + y8 + y9 ----
  hipLaunchKernelGGL(combine_out_kernel, dim3(T_TOK), dim3(256), 0, stream,
                     ycomp, ti, tw, pos, out0);
}

// Round 17
// 814.622 us; speedup vs baseline: 1.2847x; 1.2847x over previous
//
#include <hip/hip_runtime.h>
#include <hip/hip_bf16.h>

typedef unsigned short u16;
typedef __attribute__((ext_vector_type(8))) short bf16x8;
typedef __attribute__((ext_vector_type(4))) float f32x4;
typedef __attribute__((ext_vector_type(8))) unsigned short u16x8;
typedef __attribute__((ext_vector_type(4))) unsigned short u16x4;

#define T_TOK 1024
#define HID 2048
#define HEADS 16
#define Q_LORA 1536
#define KV_LORA 512
#define NOPE 128
#define ROPED 64
#define VD 128
#define N_EXP 8
#define MOE_I 1408
#define SH_I 2816
#define QKV_N 2112
#define QKV_LD 2176
#define QD 192
#define KVD 256
#define EPSF 1e-6f
#define NEG_BIG (-3.4e38f)

__device__ __forceinline__ u16 f2bf(float f) {
  union { float f; unsigned u; } x; x.f = f;
  unsigned r = x.u + 0x7fffu + ((x.u >> 16) & 1u);
  return (u16)(r >> 16);
}
__device__ __forceinline__ float bf2f(u16 h) {
  union { unsigned u; float f; } x; x.u = ((unsigned)h) << 16; return x.f;
}
__device__ __forceinline__ void split2(float f, u16& hi, u16& lo) {
  hi = f2bf(f);
  lo = f2bf(f - bf2f(hi));
}

__device__ __forceinline__ void gload16(const u16* g, const u16* l) {
  __builtin_amdgcn_global_load_lds(
      (const __attribute__((address_space(1))) void*)g,
      (__attribute__((address_space(3))) void*)l, 16, 0, 0);
}

// ================= block reductions =================
__device__ __forceinline__ float block_sum(float v, float* s) {
  #pragma unroll
  for (int o = 32; o > 0; o >>= 1) v += __shfl_down(v, o, 64);
  int w = threadIdx.x >> 6, lane = threadIdx.x & 63;
  __syncthreads();
  if (lane == 0) s[w] = v;
  __syncthreads();
  float r = s[0];
  for (int i = 1; i < 4; ++i) r += s[i];
  return r;
}
__device__ __forceinline__ float block_max(float v, float* s) {
  #pragma unroll
  for (int o = 32; o > 0; o >>= 1) v = fmaxf(v, __shfl_down(v, o, 64));
  int w = threadIdx.x >> 6, lane = threadIdx.x & 63;
  __syncthreads();
  if (lane == 0) s[w] = v;
  __syncthreads();
  float r = s[0];
  for (int i = 1; i < 4; ++i) r = fmaxf(r, s[i]);
  return r;
}

// ================= bf16 MFMA GEMM, 2-phase double-buffered K-loop (128x128 tile) =================
// direct: mode 0: C(f32)=alpha*A@B^T(+Cadd)(+causal); mode 1: Cb=silu(Cadd f32)*(alpha*acc);
//         mode 2: Cb=bf16(alpha*acc); mode 3: Cb=silu(CaddB bf16)*(alpha*acc)
// split-K (pbuf!=null): pbuf[(z*stot+soff+s)][M][ldc] = A@B^T over K-segment s
// gidx: per-row token gather for A; gcnt: per-z valid M (early exit)
// kcap: if 1, clamp kend to (T-aligned segment base)+bm+128 (causal PV; tail of A is zeros)
__global__ __launch_bounds__(256) void gemm_bf16(
    const u16* __restrict__ A, long asz, int lda,
    const u16* __restrict__ B, long bsz, int ldb,
    float* __restrict__ C, u16* __restrict__ Cb, long csz, int ldc,
    const float* __restrict__ Cadd, const u16* __restrict__ CaddB, int ldcadd,
    int K, float alpha, int causal, int mode,
    float* __restrict__ pbuf, int ksplit, int stot, int soff,
    const int* __restrict__ gidx, const int* __restrict__ gcnt, int kcap) {
  const int bm = blockIdx.y << 7, bn = blockIdx.x << 7;
  const int zz = blockIdx.z;
  const int z = (ksplit > 1) ? (zz / ksplit) : zz;
  const int s = (ksplit > 1) ? (zz % ksplit) : 0;
  if (gcnt && bm >= gcnt[z]) return;
  A += (long)z * asz; B += (long)z * bsz;
  if (C) C += (long)z * csz;
  if (Cb) Cb += (long)z * csz;
  if (Cadd && !pbuf) Cadd += (long)z * csz;
  if (CaddB) CaddB += (long)z * csz;
  const int tid = threadIdx.x, lane = tid & 63, wid = tid >> 6;

  if (causal && bn >= bm + 128) return;  // softmax masks by index; no writes needed

  __shared__ alignas(16) u16 As[2][128 * 32];
  __shared__ alignas(16) u16 Bs[2][128 * 32];

  const int wr = wid >> 1, wc = wid & 1;
  f32x4 acc[4][4];
  #pragma unroll
  for (int m = 0; m < 4; ++m)
    #pragma unroll
    for (int n = 0; n < 4; ++n) acc[m][n] = f32x4{0.f, 0.f, 0.f, 0.f};

  const int srow = (wid << 5) + (lane >> 2);
  const int scol = (lane & 3) << 3;
  const int arow = (wr << 6) + (lane & 15);
  const int brow = (wc << 6) + (lane & 15);
  const int koff = (lane >> 4) << 3;

  // A-row gather indices (loop-invariant)
  long ga0, ga1;
  {
    if (gidx) {
      const int* tk = gidx + (long)z * T_TOK;
      ga0 = (long)tk[bm + srow]; ga1 = (long)tk[bm + srow + 16];
    } else {
      ga0 = (long)(bm + srow); ga1 = (long)(bm + srow + 16);
    }
  }

  const int kseg = K / ksplit;
  const int kbeg = s * kseg;
  int kend = kbeg + kseg;
  if (kcap) {
    int segbase = (kbeg / T_TOK) * T_TOK;       // ph vs pl segment origin
    int cap = segbase + bm + 128;               // cols beyond are exact zeros in P2
    if (kend > cap) kend = cap;
  }
  int nIter = (kend - kbeg) >> 5;
  if (nIter < 0) nIter = 0;

  #define STAGE_TILE(BUF, KK)                                                 \
    {                                                                         \
      u16* asp = &As[(BUF)][(wid << 10)];                                     \
      u16* bsp = &Bs[(BUF)][(wid << 10)];                                     \
      gload16(A + ga0 * lda + (KK) + scol, asp);                              \
      gload16(A + ga1 * lda + (KK) + scol, asp + 512);                        \
      gload16(B + (long)(bn + srow) * ldb + (KK) + scol, bsp);                \
      gload16(B + (long)(bn + srow + 16) * ldb + (KK) + scol, bsp + 512);     \
    }

  if (nIter > 0) {
    STAGE_TILE(0, kbeg);
    __syncthreads();

    int cur = 0;
    for (int it = 0; it < nIter; ++it) {
      int k0 = kbeg + (it << 5);
      if (it + 1 < nIter) STAGE_TILE(cur ^ 1, k0 + 32);
      bf16x8 a[4], b[4];
      #pragma unroll
      for (int m = 0; m < 4; ++m) a[m] = *(const bf16x8*)&As[cur][((arow + (m << 4)) << 5) + koff];
      #pragma unroll
      for (int n = 0; n < 4; ++n) b[n] = *(const bf16x8*)&Bs[cur][((brow + (n << 4)) << 5) + koff];
      #pragma unroll
      for (int m = 0; m < 4; ++m)
        #pragma unroll
        for (int n = 0; n < 4; ++n)
          acc[m][n] = __builtin_amdgcn_mfma_f32_16x16x32_bf16(a[m], b[n], acc[m][n], 0, 0, 0);
      __syncthreads();
      cur ^= 1;
    }
  }
  #undef STAGE_TILE

  const int rbase = bm + (wr << 6) + ((lane >> 4) << 2);
  const int cbase = bn + (wc << 6) + (lane & 15);

  if (pbuf) {
    long pstride = (long)(gridDim.y << 7) * ldc;
    float* pp = pbuf + ((long)z * stot + soff + s) * pstride;
    #pragma unroll
    for (int m = 0; m < 4; ++m)
      #pragma unroll
      for (int j = 0; j < 4; ++j) {
        int r = rbase + (m << 4) + j;
        #pragma unroll
        for (int n = 0; n < 4; ++n) {
          int cc = cbase + (n << 4);
          pp[(long)r * ldc + cc] = acc[m][n][j];
        }
      }
    return;
  }

  #pragma unroll
  for (int m = 0; m < 4; ++m) {
    #pragma unroll
    for (int j = 0; j < 4; ++j) {
      int r = rbase + (m << 4) + j;
      #pragma unroll
      for (int n = 0; n < 4; ++n) {
        int cc = cbase + (n << 4);
        float v = acc[m][n][j] * alpha;
        if (mode == 0) {
          if (Cadd) v += Cadd[(long)r * ldcadd + cc];
          if (causal && cc > r) v = NEG_BIG;
          C[(long)r * ldc + cc] = v;
        } else if (mode == 1) {
          float gg = Cadd[(long)r * ldcadd + cc];
          float sgv = gg / (1.f + expf(-gg));
          Cb[(long)r * ldc + cc] = f2bf(sgv * v);
        } else if (mode == 2) {
          Cb[(long)r * ldc + cc] = f2bf(v);
        } else {
          float gg = bf2f(CaddB[(long)r * ldcadd + cc]);
          float sgv = gg / (1.f + expf(-gg));
          Cb[(long)r * ldc + cc] = f2bf(sgv * v);
        }
      }
    }
  }
}

// ================= split-K reduce + epilogue =================
// mode 0: C(f32)=alpha*sum+Cadd; mode 1: Cb=silu(Cadd)*alpha*sum (bf16)
// mode 2: Cb = split3 A-layout bf16: row r stride 3*ldc; [hi | lo | hi] at +0/+ldc/+2*ldc
__global__ __launch_bounds__(256) void reduce_sk(
    const float* __restrict__ pbuf, long pstride, int S,
    float* __restrict__ C, u16* __restrict__ Cb, long csz, int ldc, int Nc,
    const float* __restrict__ Cadd, long caddsz, int ldcadd,
    float alpha, int mode) {
  const int z = blockIdx.y;
  const float* pz = pbuf + (long)z * S * pstride;
  long idx = ((long)blockIdx.x * 256 + threadIdx.x) * 8;
  long r = idx / Nc; int c = (int)(idx - r * Nc);
  float a[8] = {0.f, 0.f, 0.f, 0.f, 0.f, 0.f, 0.f, 0.f};
  for (int s = 0; s < S; ++s) {
    const float* pp = pz + (long)s * pstride + idx;
    float4 x = *(const float4*)pp;
    float4 y = *(const float4*)(pp + 4);
    a[0] += x.x; a[1] += x.y; a[2] += x.z; a[3] += x.w;
    a[4] += y.x; a[5] += y.y; a[6] += y.z; a[7] += y.w;
  }
  if (mode == 0) {
    long ob = (long)z * csz + r * ldc + c;
    #pragma unroll
    for (int k = 0; k < 8; ++k) {
      float v = a[k] * alpha;
      if (Cadd) v += Cadd[(long)z * caddsz + r * ldcadd + c + k];
      C[ob + k] = v;
    }
  } else if (mode == 1) {
    long ob = (long)z * csz + r * ldc + c;
    u16x8 o;
    #pragma unroll
    for (int k = 0; k < 8; ++k) {
      float gg = Cadd[(long)z * caddsz + r * ldcadd + c + k];
      float sgv = gg / (1.f + expf(-gg));
      o[k] = f2bf(sgv * a[k] * alpha);
    }
    *(u16x8*)&Cb[ob] = o;
  } else {
    long base = r * (3L * ldc) + (long)z * csz + c;
    u16x8 hv, lv;
    #pragma unroll
    for (int k = 0; k < 8; ++k) {
      u16 hi, lo; split2(a[k] * alpha, hi, lo);
      hv[k] = hi; lv[k] = lo;
    }
    *(u16x8*)&Cb[base] = hv;
    *(u16x8*)&Cb[base + ldc] = lv;
    *(u16x8*)&Cb[base + 2 * ldc] = hv;
  }
}

// ================= transpose f32 [K][N] -> plain bf16 [Npad][K] =================
__global__ __launch_bounds__(256) void transpose_f32_bf16(
    const float* __restrict__ src, long sbs, int ld_src, int Cvalid,
    u16* __restrict__ dst, long dbs, int ld_dst) {
  __shared__ float tile[64][65];
  src += (long)blockIdx.z * sbs; dst += (long)blockIdx.z * dbs;
  const int c0 = blockIdx.x << 6, r0 = blockIdx.y << 6;
  const int tid = threadIdx.x;
  const int tc = (tid & 15) << 2, tr0 = tid >> 4;
  const bool valid = c0 < Cvalid;
  #pragma unroll
  for (int i = 0; i < 4; ++i) {
    int r = tr0 + (i << 4);
    float4 v;
    if (valid) v = *(const float4*)&src[(long)(r0 + r) * ld_src + c0 + tc];
    else { v.x = 0.f; v.y = 0.f; v.z = 0.f; v.w = 0.f; }
    tile[r][tc] = v.x; tile[r][tc + 1] = v.y; tile[r][tc + 2] = v.z; tile[r][tc + 3] = v.w;
  }
  __syncthreads();
  const int oc = tid >> 2, seg = tid & 3;
  u16x8 o0, o1;
  #pragma unroll
  for (int k = 0; k < 8; ++k) o0[k] = f2bf(tile[(seg << 4) + k][oc]);
  #pragma unroll
  for (int k = 0; k < 8; ++k) o1[k] = f2bf(tile[(seg << 4) + 8 + k][oc]);
  u16* dp = &dst[(long)(c0 + oc) * ld_dst + r0 + (seg << 4)];
  *(u16x8*)dp = o0;
  *(u16x8*)(dp + 8) = o1;
}

// ================= transpose f32 [K][N] -> split3 B-side bf16 [Npad][3K] = [hi|hi|lo] =================
__global__ __launch_bounds__(256) void transpose_split3(
    const float* __restrict__ src, long sbs, int ld_src, int Cvalid,
    u16* __restrict__ dst, long dbs, int Kp) {
  __shared__ float tile[64][65];
  src += (long)blockIdx.z * sbs; dst += (long)blockIdx.z * dbs;
  const int c0 = blockIdx.x << 6, r0 = blockIdx.y << 6;
  const int tid = threadIdx.x;
  const int tc = (tid & 15) << 2, tr0 = tid >> 4;
  const bool valid = c0 < Cvalid;
  #pragma unroll
  for (int i = 0; i < 4; ++i) {
    int r = tr0 + (i << 4);
    float4 v;
    if (valid) v = *(const float4*)&src[(long)(r0 + r) * ld_src + c0 + tc];
    else { v.x = 0.f; v.y = 0.f; v.z = 0.f; v.w = 0.f; }
    tile[r][tc] = v.x; tile[r][tc + 1] = v.y; tile[r][tc + 2] = v.z; tile[r][tc + 3] = v.w;
  }
  __syncthreads();
  const int oc = tid >> 2, seg = tid & 3;
  u16x8 h0, h1, l0, l1;
  #pragma unroll
  for (int k = 0; k < 8; ++k) {
    u16 hi, lo; split2(tile[(seg << 4) + k][oc], hi, lo);
    h0[k] = hi; l0[k] = lo;
  }
  #pragma unroll
  for (int k = 0; k < 8; ++k) {
    u16 hi, lo; split2(tile[(seg << 4) + 8 + k][oc], hi, lo);
    h1[k] = hi; l1[k] = lo;
  }
  const int ldd = 3 * Kp;
  u16* dp = &dst[(long)(c0 + oc) * ldd + r0 + (seg << 4)];
  *(u16x8*)dp = h0;            *(u16x8*)(dp + 8) = h1;
  *(u16x8*)(dp + Kp) = h0;     *(u16x8*)(dp + Kp + 8) = h1;
  *(u16x8*)(dp + 2 * Kp) = l0; *(u16x8*)(dp + 2 * Kp + 8) = l1;
}

// ================= add + RMS -> resid1(f32), h3(split3 A-side) =================
__global__ __launch_bounds__(256) void add_rms_kernel(
    const float* __restrict__ hs, const float* __restrict__ res,
    const float* __restrict__ w, float* __restrict__ resid1, u16* __restrict__ h3) {
  __shared__ float sbuf[4];
  int t = blockIdx.x;
  float v[8]; float ss = 0.f;
  #pragma unroll
  for (int i = 0; i < 8; ++i) {
    int j = threadIdx.x + (i << 8);
    float x = hs[(long)t * HID + j] + res[(long)t * HID + j];
    v[i] = x; resid1[(long)t * HID + j] = x; ss += x * x;
  }
  ss = block_sum(ss, sbuf);
  float sc = rsqrtf(ss / (float)HID + EPSF);
  u16* base = h3 + (long)t * (3 * HID);
  #pragma unroll
  for (int i = 0; i < 8; ++i) {
    int j = threadIdx.x + (i << 8);
    u16 hi, lo; split2(v[i] * sc * w[j], hi, lo);
    base[j] = hi; base[HID + j] = lo; base[2 * HID + j] = hi;
  }
}

// ================= row RMS -> split3 or plain bf16 (+f32) =================
template <int NW, bool SPLIT, bool WF32>
__global__ __launch_bounds__(256) void rms_rows_kernel(
    const float* __restrict__ in, int ldin, const float* __restrict__ w,
    u16* __restrict__ outb, float* __restrict__ outf) {
  __shared__ float sbuf[4];
  int t = blockIdx.x;
  const int W = NW * 256;
  float v[NW]; float ss = 0.f;
  #pragma unroll
  for (int i = 0; i < NW; ++i) {
    int j = threadIdx.x + (i << 8);
    float x = in[(long)t * ldin + j];
    v[i] = x; ss += x * x;
  }
  ss = block_sum(ss, sbuf);
  float sc = rsqrtf(ss / (float)W + EPSF);
  #pragma unroll
  for (int i = 0; i < NW; ++i) {
    int j = threadIdx.x + (i << 8);
    float y = v[i] * sc * w[j];
    if (SPLIT) {
      u16 hi, lo; split2(y, hi, lo);
      u16* base = outb + (long)t * (3 * W);
      base[j] = hi; base[W + j] = lo; base[2 * W + j] = hi;
    } else {
      outb[(long)t * W + j] = f2bf(y);
    }
    if (WF32) outf[(long)t * W + j] = y;
  }
}

// ================= RoPE (f32, in place on qbuf; qkv k_pe -> kpe) =================
__global__ __launch_bounds__(256) void rope_kernel(
    const int* __restrict__ pos, float* __restrict__ q,
    const float* __restrict__ qkv, float* __restrict__ kpe) {
  int t = blockIdx.x;
  float fp = (float)pos[t];
  for (int item = threadIdx.x; item < 544; item += 256) {
    int i = item & 31;
    float inv = expf(-((float)i * (2.f / 64.f)) * 9.210340371976184f);
    float ang = fp * inv;
    float c = cosf(ang), s = sinf(ang);
    if (item < 512) {
      int hh = item >> 5;
      long base = (long)t * (HEADS * QD) + hh * QD + NOPE;
      float x1 = q[base + i], x2 = q[base + 32 + i];
      q[base + i] = x1 * c - x2 * s;
      q[base + 32 + i] = x2 * c + x1 * s;
    } else {
      long base = (long)t * QKV_LD + (Q_LORA + KV_LORA);
      float x1 = qkv[base + i], x2 = qkv[base + 32 + i];
      kpe[(long)t * 64 + i] = x1 * c - x2 * s;
      kpe[(long)t * 64 + 32 + i] = x2 * c + x1 * s;
    }
  }
}

// ================= q3 per head: A-side [16][T][3*192] = [hi|lo|hi] =================
__global__ __launch_bounds__(192) void build_q3_kernel(
    const float* __restrict__ qbuf, u16* __restrict__ q3) {
  int t = blockIdx.x, h = blockIdx.y, d = threadIdx.x;
  float x = qbuf[(long)t * (HEADS * QD) + h * QD + d];
  u16 hi, lo; split2(x, hi, lo);
  u16* base = q3 + ((long)h * T_TOK + t) * (3 * QD);
  base[d] = hi; base[QD + d] = lo; base[2 * QD + d] = hi;
}

// ================= kmat3 per head: B-side [16][T][3*192] = [hi|hi|lo] =================
__global__ __launch_bounds__(192) void build_kmat3_kernel(
    const float* __restrict__ kv, const float* __restrict__ kpe,
    u16* __restrict__ kmat3) {
  int t = blockIdx.x, h = blockIdx.y, d = threadIdx.x;
  float v = (d < NOPE) ? kv[(long)t * (HEADS * KVD) + h * KVD + d]
                       : kpe[(long)t * 64 + (d - NOPE)];
  u16 hi, lo; split2(v, hi, lo);
  u16* base = kmat3 + ((long)h * T_TOK + t) * (3 * QD);
  base[d] = hi; base[QD + d] = hi; base[2 * QD + d] = lo;
}

// ================= masked softmax row -> P2 [row][2*1024] = [hi|lo] (prefix-only loads) =================
__global__ __launch_bounds__(256) void softmax_kernel(
    const float* __restrict__ S, u16* __restrict__ P2) {
  __shared__ float sbuf[4];
  long row = blockIdx.x;
  int r = (int)(row & (T_TOK - 1));
  const float* p = S + row * T_TOK;
  int c0 = threadIdx.x << 2;
  float4 v;
  if (c0 <= r) {
    v = ((const float4*)p)[threadIdx.x];
    if (c0 + 1 > r) v.y = NEG_BIG;
    if (c0 + 2 > r) v.z = NEG_BIG;
    if (c0 + 3 > r) v.w = NEG_BIG;
  } else {
    v.x = NEG_BIG; v.y = NEG_BIG; v.z = NEG_BIG; v.w = NEG_BIG;
  }
  float m = fmaxf(fmaxf(v.x, v.y), fmaxf(v.z, v.w));
  m = block_max(m, sbuf);
  v.x = expf(v.x - m); v.y = expf(v.y - m); v.z = expf(v.z - m); v.w = expf(v.w - m);
  float s = v.x + v.y + v.z + v.w;
  s = block_sum(s, sbuf);
  float inv = 1.f / s;
  u16x4 hv, lv;
  u16 hi, lo;
  split2(v.x * inv, hi, lo); hv[0] = hi; lv[0] = lo;
  split2(v.y * inv, hi, lo); hv[1] = hi; lv[1] = lo;
  split2(v.z * inv, hi, lo); hv[2] = hi; lv[2] = lo;
  split2(v.w * inv, hi, lo); hv[3] = hi; lv[3] = lo;
  u16* base = P2 + row * (2 * T_TOK) + (threadIdx.x << 2);
  *(u16x4*)base = hv;
  *(u16x4*)(base + T_TOK) = lv;
}

// ================= gate + top-2 -> ti[t][2], tw[t][2] =================
__global__ __launch_bounds__(256) void gate_topk_kernel(
    const float* __restrict__ h2, const float* __restrict__ gw,
    int* __restrict__ ti, float* __restrict__ tw) {
  __shared__ float sbuf[4];
  __shared__ float lg[N_EXP];
  int t = blockIdx.x;
  float p[N_EXP] = {0.f, 0.f, 0.f, 0.f, 0.f, 0.f, 0.f, 0.f};
  for (int j = threadIdx.x; j < HID; j += 256) {
    float x = h2[(long)t * HID + j];
    const float* gr = gw + (long)j * N_EXP;
    #pragma unroll
    for (int e = 0; e < N_EXP; ++e) p[e] += x * gr[e];
  }
  #pragma unroll
  for (int e = 0; e < N_EXP; ++e) {
    float s = block_sum(p[e], sbuf);
    if (threadIdx.x == 0) lg[e] = s;
  }
  __syncthreads();
  if (threadIdx.x == 0) {
    float m = lg[0];
    for (int e = 1; e < N_EXP; ++e) m = fmaxf(m, lg[e]);
    float pe[N_EXP]; float s = 0.f;
    for (int e = 0; e < N_EXP; ++e) { pe[e] = expf(lg[e] - m); s += pe[e]; }
    for (int e = 0; e < N_EXP; ++e) pe[e] /= s;
    int i0 = 0;
    for (int e = 1; e < N_EXP; ++e) if (pe[e] > pe[i0]) i0 = e;
    int i1 = -1;
    for (int e = 0; e < N_EXP; ++e) if (e != i0 && (i1 < 0 || pe[e] > pe[i1])) i1 = e;
    float ssum = pe[i0] + pe[i1];
    ti[2 * t] = i0; ti[2 * t + 1] = i1;
    tw[2 * t] = pe[i0] / ssum; tw[2 * t + 1] = pe[i1] / ssum;
  }
}

// ================= routing lists for 20 z-slices (z and z+10 identical): tokidx20, cnt20, pos =================
__global__ __launch_bounds__(64) void route_build_kernel(
    const int* __restrict__ ti, int* __restrict__ tokidx,
    int* __restrict__ pos, int* __restrict__ cnt) {
  int e = blockIdx.x;            // 0..19
  int le = (e < 10) ? e : e - 10;
  int lane = threadIdx.x;
  if (le >= N_EXP) {  // shared virtual experts: identity
    for (int p = lane; p < T_TOK; p += 64) tokidx[(long)e * T_TOK + p] = p;
    if (lane == 0) cnt[e] = T_TOK;
    return;
  }
  int c = 0;
  for (int base = 0; base < T_TOK; base += 64) {
    int t = base + lane;
    int e0 = ti[2 * t], e1 = ti[2 * t + 1];
    bool match = (e0 == le) || (e1 == le);
    unsigned long long mask = __ballot(match);
    int pref = __popcll(mask & ((1ull << lane) - 1ull));
    if (match) {
      int p = c + pref;
      tokidx[(long)e * T_TOK + p] = t;
      if (e < 10) pos[2 * t + ((e0 == le) ? 0 : 1)] = p;
    }
    c += __popcll(mask);
  }
  for (int p = c + lane; p < T_TOK; p += 64) tokidx[(long)e * T_TOK + p] = 0;
  if (lane == 0) cnt[e] = c;
}

// ================= silu over split gate|up z-slices: gact[e][r][i] = silu(gug[e][r][i]) * gug[e+10][r][i] =================
__global__ __launch_bounds__(256) void silu_mul_moe_kernel(
    const u16* __restrict__ gug, const int* __restrict__ cnt,
    u16* __restrict__ gact) {
  int r = blockIdx.x, e = blockIdx.y;
  int padded = (cnt[e] + 127) & ~127;
  if (r >= padded) return;
  int j = threadIdx.x << 3;
  if (j >= MOE_I) return;
  u16x8 gv = *(const u16x8*)&gug[((long)e * T_TOK + r) * MOE_I + j];
  u16x8 uv = *(const u16x8*)&gug[(((long)e + 10) * T_TOK + r) * MOE_I + j];
  u16x8 o;
  #pragma unroll
  for (int k = 0; k < 8; ++k) {
    float g = bf2f(gv[k]);
    o[k] = f2bf(g / (1.f + expf(-g)) * bf2f(uv[k]));
  }
  *(u16x8*)&gact[((long)e * T_TOK + r) * MOE_I + j] = o;
}

// ================= out0[t] = tw0*y[e0][p0] + tw1*y[e1][p1] + y[8][t] + y[9][t] =================
__global__ __launch_bounds__(256) void combine_out_kernel(
    const u16* __restrict__ y, const int* __restrict__ ti,
    const float* __restrict__ tw, const int* __restrict__ pos,
    float* __restrict__ out0) {
  int t = blockIdx.x;
  int j = threadIdx.x << 3;
  int e0 = ti[2 * t], e1 = ti[2 * t + 1];
  int p0 = pos[2 * t], p1 = pos[2 * t + 1];
  float w0 = tw[2 * t], w1 = tw[2 * t + 1];
  u16x8 a = *(const u16x8*)&y[((long)e0 * T_TOK + p0) * HID + j];
  u16x8 b = *(const u16x8*)&y[((long)e1 * T_TOK + p1) * HID + j];
  u16x8 c = *(const u16x8*)&y[((long)8 * T_TOK + t) * HID + j];
  u16x8 d = *(const u16x8*)&y[((long)9 * T_TOK + t) * HID + j];
  float* rp = out0 + (long)t * HID + j;
  #pragma unroll
  for (int k = 0; k < 8; ++k)
    rp[k] = w0 * bf2f(a[k]) + w1 * bf2f(b[k]) + bf2f(c[k]) + bf2f(d[k]);
}

// ================= launcher =================
extern "C" void kernel_launch(void* const* d_in, const int* in_sizes, int n_in,
                              void* d_out, int out_size, void* d_ws, size_t ws_size,
                              hipStream_t stream) {
  (void)in_sizes; (void)n_in; (void)out_size; (void)ws_size;
  const int*   positions = (const int*)d_in[0];
  const float* hs        = (const float*)d_in[1];
  const float* res       = (const float*)d_in[2];
  const float* w_in_ln   = (const float*)d_in[3];
  const float* w_post_ln = (const float*)d_in[4];
  const float* w_q_ln    = (const float*)d_in[5];
  const float* w_kv_ln   = (const float*)d_in[6];
  const float* w_qkv_a   = (const float*)d_in[7];
  const float* w_q_b     = (const float*)d_in[8];
  const float* w_kv_b    = (const float*)d_in[9];
  const float* w_o       = (const float*)d_in[10];
  const float* gate_w    = (const float*)d_in[11];
  const float* we_gate   = (const float*)d_in[12];
  const float* we_up     = (const float*)d_in[13];
  const float* we_down   = (const float*)d_in[14];
  const float* ws_gate   = (const float*)d_in[15];
  const float* ws_up     = (const float*)d_in[16];
  const float* ws_dn     = (const float*)d_in[17];

  float* out0   = (float*)d_out;
  float* resid2 = out0 + (long)T_TOK * HID;

  char* Wb = (char*)d_ws;
  size_t off = 0;
  #define CARVE(name, type, bytes) type* name = (type*)(Wb + off); off += (((size_t)(bytes) + 255) & ~(size_t)255)

  // ---- W1: persistent split3 attention weights ----
  CARVE(wqkvaT3, u16, (size_t)QKV_LD * 3 * HID * 2);
  CARVE(wqbT3,   u16, (size_t)(HEADS * QD) * 3 * Q_LORA * 2);
  CARVE(wkvbT3,  u16, (size_t)(HEADS * KVD) * 3 * KV_LORA * 2);
  CARVE(woT3,    u16, (size_t)HID * 3 * HID * 2);

  size_t pool = off;
  // ---- phase A scratch ----
  CARVE(resid1, float, (size_t)T_TOK * HID * 4);
  CARVE(h3,     u16,   (size_t)T_TOK * 3 * HID * 2);
  CARVE(qkv,    float, (size_t)T_TOK * QKV_LD * 4);
  CARVE(qc3,    u16,   (size_t)T_TOK * 3 * Q_LORA * 2);
  CARVE(kvc3,   u16,   (size_t)T_TOK * 3 * KV_LORA * 2);
  CARVE(qbuf,   float, (size_t)T_TOK * HEADS * QD * 4);
  CARVE(q3,     u16,   (size_t)HEADS * T_TOK * 3 * QD * 2);
  CARVE(kvbuf,  float, (size_t)T_TOK * HEADS * KVD * 4);
  CARVE(kpe,    float, (size_t)T_TOK * 64 * 4);
  CARVE(kmat3,  u16,   (size_t)HEADS * T_TOK * 3 * QD * 2);
  CARVE(vt3,    u16,   (size_t)HEADS * VD * 3 * T_TOK * 2);
  CARVE(scores, float, (size_t)HEADS * T_TOK * T_TOK * 4);   // doubles as phase-A split-K pbuf
  CARVE(P2,     u16,   (size_t)HEADS * T_TOK * 2 * T_TOK * 2);
  CARVE(attn3,  u16,   (size_t)T_TOK * 3 * HID * 2);
  size_t endA = off;
  float* pbufA = scores;

  // ---- phase B (aliases phase A; written only after step 11) ----
  off = pool;
  CARVE(wegu20, u16, (size_t)20 * MOE_I * HID * 2);   // [0..9]=gate (8 routed + 2 shared), [10..19]=up
  CARVE(wedT10, u16, (size_t)10 * HID * MOE_I * 2);
  CARVE(h2,     float, (size_t)T_TOK * HID * 4);
  CARVE(h2_b,   u16,   (size_t)T_TOK * HID * 2);
  CARVE(ti,     int,   (size_t)T_TOK * 2 * 4);
  CARVE(tw,     float, (size_t)T_TOK * 2 * 4);
  CARVE(pos,    int,   (size_t)T_TOK * 2 * 4);
  CARVE(tokidx20, int, (size_t)20 * T_TOK * 4);
  CARVE(cnt20,  int,   128);
  CARVE(gug20,  u16,   (size_t)20 * T_TOK * MOE_I * 2);
  CARVE(gact,   u16,   (size_t)10 * T_TOK * MOE_I * 2);
  CARVE(ycomp,  u16,   (size_t)10 * T_TOK * HID * 2);
  if (off < endA) off = endA;
  #undef CARVE

  u16* wegT10 = wegu20;                                  // gate slices
  u16* weuT10 = wegu20 + (size_t)10 * MOE_I * HID;       // up slices

  const float* nullf = nullptr;
  float* nullC = nullptr;
  u16* nullB = nullptr;
  const u16* nullBB = nullptr;
  const int* nullI = nullptr;

  // ---- 0. attention weight transposes (split3) ----
  hipLaunchKernelGGL(transpose_split3, dim3(QKV_LD / 64, HID / 64, 1), dim3(256), 0, stream,
                     w_qkv_a, 0L, QKV_N, QKV_N, wqkvaT3, 0L, HID);
  hipLaunchKernelGGL(transpose_split3, dim3(HEADS * QD / 64, Q_LORA / 64, 1), dim3(256), 0, stream,
                     w_q_b, 0L, HEADS * QD, HEADS * QD, wqbT3, 0L, Q_LORA);
  hipLaunchKernelGGL(transpose_split3, dim3(HEADS * KVD / 64, KV_LORA / 64, 1), dim3(256), 0, stream,
                     w_kv_b, 0L, HEADS * KVD, HEADS * KVD, wkvbT3, 0L, KV_LORA);
  hipLaunchKernelGGL(transpose_split3, dim3(HID / 64, HID / 64, 1), dim3(256), 0, stream,
                     w_o, 0L, HID, HID, woT3, 0L, HID);

  // ---- 1. resid1 = hs+res; h3 = split3(rms) ----
  hipLaunchKernelGGL(add_rms_kernel, dim3(T_TOK), dim3(256), 0, stream,
                     hs, res, w_in_ln, resid1, h3);
  // ---- 2. qkv = h @ w_qkv_a (split3 K'=6144, split-K 4) ----
  hipLaunchKernelGGL(gemm_bf16, dim3(QKV_LD / 128, T_TOK / 128, 4), dim3(256), 0, stream,
                     h3, 0L, 3 * HID, wqkvaT3, 0L, 3 * HID,
                     nullC, nullB, 0L, QKV_LD, nullf, nullBB, 0, 3 * HID, 1.f, 0, 0,
                     pbufA, 4, 4, 0, nullI, nullI, 0);
  hipLaunchKernelGGL(reduce_sk, dim3(T_TOK * QKV_LD / 2048, 1), dim3(256), 0, stream,
                     pbufA, (long)T_TOK * QKV_LD, 4,
                     qkv, nullB, 0L, QKV_LD, QKV_LD, nullf, 0L, 0, 1.f, 0);
  // ---- 3. q_c, kv_c RMS -> split3 ----
  hipLaunchKernelGGL((rms_rows_kernel<6, true, false>), dim3(T_TOK), dim3(256), 0, stream,
                     qkv, QKV_LD, w_q_ln, qc3, (float*)nullptr);
  hipLaunchKernelGGL((rms_rows_kernel<2, true, false>), dim3(T_TOK), dim3(256), 0, stream,
                     qkv + Q_LORA, QKV_LD, w_kv_ln, kvc3, (float*)nullptr);
  // ---- 4. q = q_c @ w_q_b (split3 K'=4608, split-K 4) ----
  hipLaunchKernelGGL(gemm_bf16, dim3(HEADS * QD / 128, T_TOK / 128, 4), dim3(256), 0, stream,
                     qc3, 0L, 3 * Q_LORA, wqbT3, 0L, 3 * Q_LORA,
                     nullC, nullB, 0L, HEADS * QD, nullf, nullBB, 0, 3 * Q_LORA, 1.f, 0, 0,
                     pbufA, 4, 4, 0, nullI, nullI, 0);
  hipLaunchKernelGGL(reduce_sk, dim3(T_TOK * HEADS * QD / 2048, 1), dim3(256), 0, stream,
                     pbufA, (long)T_TOK * HEADS * QD, 4,
                     qbuf, nullB, 0L, HEADS * QD, HEADS * QD, nullf, 0L, 0, 1.f, 0);
  // ---- 5. kv = kv_c @ w_kv_b (split3 K'=1536, split-K 4) ----
  hipLaunchKernelGGL(gemm_bf16, dim3(HEADS * KVD / 128, T_TOK / 128, 4), dim3(256), 0, stream,
                     kvc3, 0L, 3 * KV_LORA, wkvbT3, 0L, 3 * KV_LORA,
                     nullC, nullB, 0L, HEADS * KVD, nullf, nullBB, 0, 3 * KV_LORA, 1.f, 0, 0,
                     pbufA, 4, 4, 0, nullI, nullI, 0);
  hipLaunchKernelGGL(reduce_sk, dim3(T_TOK * HEADS * KVD / 2048, 1), dim3(256), 0, stream,
                     pbufA, (long)T_TOK * HEADS * KVD, 4,
                     kvbuf, nullB, 0L, HEADS * KVD, HEADS * KVD, nullf, 0L, 0, 1.f, 0);
  // ---- 6. RoPE ----
  hipLaunchKernelGGL(rope_kernel, dim3(T_TOK), dim3(256), 0, stream,
                     positions, qbuf, qkv, kpe);
  // ---- 7. q3, kmat3, vt3 ----
  hipLaunchKernelGGL(build_q3_kernel, dim3(T_TOK, HEADS), dim3(192), 0, stream, qbuf, q3);
  hipLaunchKernelGGL(build_kmat3_kernel, dim3(T_TOK, HEADS), dim3(192), 0, stream,
                     kvbuf, kpe, kmat3);
  hipLaunchKernelGGL(transpose_split3, dim3(VD / 64, T_TOK / 64, HEADS), dim3(256), 0, stream,
                     kvbuf + NOPE, 256L, HEADS * KVD, VD, vt3, (long)VD * 3 * T_TOK, T_TOK);
  // ---- 8. scores (split3 K'=576, causal; masked tiles skipped) ----
  hipLaunchKernelGGL(gemm_bf16, dim3(T_TOK / 128, T_TOK / 128, HEADS), dim3(256), 0, stream,
                     q3, (long)T_TOK * 3 * QD, 3 * QD,
                     kmat3, (long)T_TOK * 3 * QD, 3 * QD,
                     scores, nullB, (long)T_TOK * T_TOK, T_TOK,
                     nullf, nullBB, 0, 576, 0.07216878364870322f, 1, 0,
                     nullC, 1, 1, 0, nullI, nullI, 0);
  // ---- 9. masked softmax (prefix-only reads) -> P2 [hi|lo] ----
  hipLaunchKernelGGL(softmax_kernel, dim3(HEADS * T_TOK), dim3(256), 0, stream, scores, P2);
  // ---- 10. PV with causal K-clamp: [ph|pl]@[vh|vh] (K=2048, S=4) + ph@vl (K=1024, S=2) ----
  hipLaunchKernelGGL(gemm_bf16, dim3(VD / 128, T_TOK / 128, HEADS * 4), dim3(256), 0, stream,
                     P2, (long)T_TOK * 2 * T_TOK, 2 * T_TOK,
                     vt3, (long)VD * 3 * T_TOK, 3 * T_TOK,
                     nullC, nullB, 0L, VD, nullf, nullBB, 0, 2 * T_TOK, 1.f, 0, 0,
                     pbufA, 4, 6, 0, nullI, nullI, 1);
  hipLaunchKernelGGL(gemm_bf16, dim3(VD / 128, T_TOK / 128, HEADS * 2), dim3(256), 0, stream,
                     P2, (long)T_TOK * 2 * T_TOK, 2 * T_TOK,
                     vt3 + 2 * T_TOK, (long)VD * 3 * T_TOK, 3 * T_TOK,
                     nullC, nullB, 0L, VD, nullf, nullBB, 0, T_TOK, 1.f, 0, 0,
                     pbufA, 2, 6, 4, nullI, nullI, 1);
  // reduce writes attn3 (split3 A-layout) directly: mode 2
  hipLaunchKernelGGL(reduce_sk, dim3(T_TOK * VD / 2048, HEADS), dim3(256), 0, stream,
                     pbufA, (long)T_TOK * VD, 6,
                     nullC, attn3, (long)VD, HID, VD, nullf, 0L, 0, 1.f, 2);
  // ---- 11. resid2 = resid1 + attn @ w_o (split3 K'=6144, split-K 4) ----
  hipLaunchKernelGGL(gemm_bf16, dim3(HID / 128, T_TOK / 128, 4), dim3(256), 0, stream,
                     attn3, 0L, 3 * HID, woT3, 0L, 3 * HID,
                     nullC, nullB, 0L, HID, nullf, nullBB, 0, 3 * HID, 1.f, 0, 0,
                     pbufA, 4, 4, 0, nullI, nullI, 0);
  hipLaunchKernelGGL(reduce_sk, dim3(T_TOK * HID / 2048, 1), dim3(256), 0, stream,
                     pbufA, (long)T_TOK * HID, 4,
                     resid2, nullB, 0L, HID, HID, resid1, 0L, HID, 1.f, 0);

  // ---- phase-B weight transposes: [gate×10 | up×10] + down×10 ----
  hipLaunchKernelGGL(transpose_f32_bf16, dim3(MOE_I / 64, HID / 64, N_EXP), dim3(256), 0, stream,
                     we_gate, (long)HID * MOE_I, MOE_I, MOE_I, wegT10, (long)MOE_I * HID, HID);
  hipLaunchKernelGGL(transpose_f32_bf16, dim3(MOE_I / 64, HID / 64, 2), dim3(256), 0, stream,
                     ws_gate, (long)MOE_I, SH_I, MOE_I,
                     wegT10 + (size_t)8 * MOE_I * HID, (long)MOE_I * HID, HID);
  hipLaunchKernelGGL(transpose_f32_bf16, dim3(MOE_I / 64, HID / 64, N_EXP), dim3(256), 0, stream,
                     we_up, (long)HID * MOE_I, MOE_I, MOE_I, weuT10, (long)MOE_I * HID, HID);
  hipLaunchKernelGGL(transpose_f32_bf16, dim3(MOE_I / 64, HID / 64, 2), dim3(256), 0, stream,
                     ws_up, (long)MOE_I, SH_I, MOE_I,
                     weuT10 + (size_t)8 * MOE_I * HID, (long)MOE_I * HID, HID);
  hipLaunchKernelGGL(transpose_f32_bf16, dim3(HID / 64, MOE_I / 64, N_EXP), dim3(256), 0, stream,
                     we_down, (long)MOE_I * HID, HID, HID, wedT10, (long)HID * MOE_I, MOE_I);
  hipLaunchKernelGGL(transpose_f32_bf16, dim3(HID / 64, MOE_I / 64, 2), dim3(256), 0, stream,
                     ws_dn, (long)MOE_I * HID, HID, HID,
                     wedT10 + (size_t)8 * HID * MOE_I, (long)HID * MOE_I, MOE_I);

  // ---- 12. h2 = rms(resid2) ----
  hipLaunchKernelGGL((rms_rows_kernel<8, false, true>), dim3(T_TOK), dim3(256), 0, stream,
                     resid2, HID, w_post_ln, h2_b, h2);
  // ---- 13. gating + routing lists (20 z-slices) ----
  hipLaunchKernelGGL(gate_topk_kernel, dim3(T_TOK), dim3(256), 0, stream,
                     h2, gate_w, ti, tw);
  hipLaunchKernelGGL(route_build_kernel, dim3(20), dim3(64), 0, stream,
                     ti, tokidx20, pos, cnt20);
  // ---- 14. gate+up in ONE 20-z launch (mode 2, gathered) -> gug20; silu -> gact ----
  hipLaunchKernelGGL(gemm_bf16, dim3(MOE_I / 128, T_TOK / 128, 20), dim3(256), 0, stream,
                     h2_b, 0L, HID, wegu20, (long)MOE_I * HID, HID,
                     nullC, gug20, (long)T_TOK * MOE_I, MOE_I,
                     nullf, nullBB, 0, HID, 1.f, 0, 2, nullC, 1, 1, 0, tokidx20, cnt20, 0);
  hipLaunchKernelGGL(silu_mul_moe_kernel, dim3(T_TOK, 10), dim3(256), 0, stream,
                     gug20, cnt20, gact);
  // ---- 15. down over compact rows -> ycomp (mode 2, cnt-guarded) ----
  hipLaunchKernelGGL(gemm_bf16, dim3(HID / 128, T_TOK / 128, 10), dim3(256), 0, stream,
                     gact, (long)T_TOK * MOE_I, MOE_I,
                     wedT10, (long)HID * MOE_I, MOE_I,
                     nullC, ycomp, (long)T_TOK * HID, HID,
                     nullf, nullBB, 0, MOE_I, 1.f, 0, 2, nullC, 1, 1, 0, nullI, cnt20, 0);
  // ---- 16. combine: out0 = tw0*y[e0][p0] + tw1*y[e1][p1] + y8 + y9 ----
  hipLaunchKernelGGL(combine_out_kernel, dim3(T_TOK), dim3(256), 0, stream,
                     ycomp, ti, tw, pos, out0);
}

// Round 18
// 794.535 us; speedup vs baseline: 1.3172x; 1.0253x over previous
//
#include <hip/hip_runtime.h>
#include <hip/hip_bf16.h>

typedef unsigned short u16;
typedef __attribute__((ext_vector_type(8))) short bf16x8;
typedef __attribute__((ext_vector_type(4))) float f32x4;
typedef __attribute__((ext_vector_type(8))) unsigned short u16x8;
typedef __attribute__((ext_vector_type(4))) unsigned short u16x4;

#define T_TOK 1024
#define HID 2048
#define HEADS 16
#define Q_LORA 1536
#define KV_LORA 512
#define NOPE 128
#define ROPED 64
#define VD 128
#define N_EXP 8
#define MOE_I 1408
#define SH_I 2816
#define QKV_N 2112
#define QKV_LD 2176
#define QD 192
#define KVD 256
#define EPSF 1e-6f
#define NEG_BIG (-3.4e38f)

__device__ __forceinline__ u16 f2bf(float f) {
  union { float f; unsigned u; } x; x.f = f;
  unsigned r = x.u + 0x7fffu + ((x.u >> 16) & 1u);
  return (u16)(r >> 16);
}
__device__ __forceinline__ float bf2f(u16 h) {
  union { unsigned u; float f; } x; x.u = ((unsigned)h) << 16; return x.f;
}
__device__ __forceinline__ void split2(float f, u16& hi, u16& lo) {
  hi = f2bf(f);
  lo = f2bf(f - bf2f(hi));
}

__device__ __forceinline__ void gload16(const u16* g, const u16* l) {
  __builtin_amdgcn_global_load_lds(
      (const __attribute__((address_space(1))) void*)g,
      (__attribute__((address_space(3))) void*)l, 16, 0, 0);
}

// ================= block reductions =================
__device__ __forceinline__ float block_sum(float v, float* s) {
  #pragma unroll
  for (int o = 32; o > 0; o >>= 1) v += __shfl_down(v, o, 64);
  int w = threadIdx.x >> 6, lane = threadIdx.x & 63;
  __syncthreads();
  if (lane == 0) s[w] = v;
  __syncthreads();
  float r = s[0];
  for (int i = 1; i < 4; ++i) r += s[i];
  return r;
}
__device__ __forceinline__ float block_max(float v, float* s) {
  #pragma unroll
  for (int o = 32; o > 0; o >>= 1) v = fmaxf(v, __shfl_down(v, o, 64));
  int w = threadIdx.x >> 6, lane = threadIdx.x & 63;
  __syncthreads();
  if (lane == 0) s[w] = v;
  __syncthreads();
  float r = s[0];
  for (int i = 1; i < 4; ++i) r = fmaxf(r, s[i]);
  return r;
}

// ================= bf16 MFMA GEMM, 2-phase double-buffered K-loop (128x128 tile) =================
// direct: mode 0: C(f32)=alpha*A@B^T(+Cadd)(+causal); mode 1: Cb=silu(Cadd f32)*(alpha*acc);
//         mode 2: Cb=bf16(alpha*acc); mode 3: Cb=silu(CaddB bf16)*(alpha*acc)
// split-K (pbuf!=null): pbuf[(z*stot+soff+s)][M][ldc] = A@B^T over K-segment s
// gidx: per-row token gather for A; gcnt: per-z valid M (early exit)
// kcap: if 1, clamp kend to (T-aligned segment base)+bm+128 (causal PV; tail of A is zeros)
// swz: pair-balanced XCD swizzle — co-locate each (M,z) pair's N-blocks on one XCD,
//      pairs round-robin across XCDs with z decoded fastest (load balance). Requires
//      gridDim.y*gridDim.z % 8 == 0. Perf heuristic only.
__global__ __launch_bounds__(256) void gemm_bf16(
    const u16* __restrict__ A, long asz, int lda,
    const u16* __restrict__ B, long bsz, int ldb,
    float* __restrict__ C, u16* __restrict__ Cb, long csz, int ldc,
    const float* __restrict__ Cadd, const u16* __restrict__ CaddB, int ldcadd,
    int K, float alpha, int causal, int mode,
    float* __restrict__ pbuf, int ksplit, int stot, int soff,
    const int* __restrict__ gidx, const int* __restrict__ gcnt, int kcap, int swz) {
  int bxi, byi, zz;
  if (swz) {
    int gx = gridDim.x, gz = gridDim.z;
    int f = blockIdx.x + gx * (blockIdx.y + gridDim.y * blockIdx.z);
    int r = f & 7, s = f >> 3;
    bxi = s % gx;
    int g = r + 8 * (s / gx);      // pair id in [0, gy*gz)
    zz  = g % gz;
    byi = g / gz;
  } else {
    bxi = blockIdx.x; byi = blockIdx.y; zz = blockIdx.z;
  }
  const int bm = byi << 7, bn = bxi << 7;
  const int z = (ksplit > 1) ? (zz / ksplit) : zz;
  const int s = (ksplit > 1) ? (zz % ksplit) : 0;
  if (gcnt && bm >= gcnt[z]) return;
  A += (long)z * asz; B += (long)z * bsz;
  if (C) C += (long)z * csz;
  if (Cb) Cb += (long)z * csz;
  if (Cadd && !pbuf) Cadd += (long)z * csz;
  if (CaddB) CaddB += (long)z * csz;
  const int tid = threadIdx.x, lane = tid & 63, wid = tid >> 6;

  if (causal && bn >= bm + 128) return;  // softmax masks by index; no writes needed

  __shared__ alignas(16) u16 As[2][128 * 32];
  __shared__ alignas(16) u16 Bs[2][128 * 32];

  const int wr = wid >> 1, wc = wid & 1;
  f32x4 acc[4][4];
  #pragma unroll
  for (int m = 0; m < 4; ++m)
    #pragma unroll
    for (int n = 0; n < 4; ++n) acc[m][n] = f32x4{0.f, 0.f, 0.f, 0.f};

  const int srow = (wid << 5) + (lane >> 2);
  const int scol = (lane & 3) << 3;
  const int arow = (wr << 6) + (lane & 15);
  const int brow = (wc << 6) + (lane & 15);
  const int koff = (lane >> 4) << 3;

  // A-row gather indices (loop-invariant)
  long ga0, ga1;
  {
    if (gidx) {
      const int* tk = gidx + (long)z * T_TOK;
      ga0 = (long)tk[bm + srow]; ga1 = (long)tk[bm + srow + 16];
    } else {
      ga0 = (long)(bm + srow); ga1 = (long)(bm + srow + 16);
    }
  }

  const int kseg = K / ksplit;
  const int kbeg = s * kseg;
  int kend = kbeg + kseg;
  if (kcap) {
    int segbase = (kbeg / T_TOK) * T_TOK;       // ph vs pl segment origin
    int cap = segbase + bm + 128;               // cols beyond are exact zeros in P2
    if (kend > cap) kend = cap;
  }
  int nIter = (kend - kbeg) >> 5;
  if (nIter < 0) nIter = 0;

  #define STAGE_TILE(BUF, KK)                                                 \
    {                                                                         \
      u16* asp = &As[(BUF)][(wid << 10)];                                     \
      u16* bsp = &Bs[(BUF)][(wid << 10)];                                     \
      gload16(A + ga0 * lda + (KK) + scol, asp);                              \
      gload16(A + ga1 * lda + (KK) + scol, asp + 512);                        \
      gload16(B + (long)(bn + srow) * ldb + (KK) + scol, bsp);                \
      gload16(B + (long)(bn + srow + 16) * ldb + (KK) + scol, bsp + 512);     \
    }

  if (nIter > 0) {
    STAGE_TILE(0, kbeg);
    __syncthreads();

    int cur = 0;
    for (int it = 0; it < nIter; ++it) {
      int k0 = kbeg + (it << 5);
      if (it + 1 < nIter) STAGE_TILE(cur ^ 1, k0 + 32);
      bf16x8 a[4], b[4];
      #pragma unroll
      for (int m = 0; m < 4; ++m) a[m] = *(const bf16x8*)&As[cur][((arow + (m << 4)) << 5) + koff];
      #pragma unroll
      for (int n = 0; n < 4; ++n) b[n] = *(const bf16x8*)&Bs[cur][((brow + (n << 4)) << 5) + koff];
      #pragma unroll
      for (int m = 0; m < 4; ++m)
        #pragma unroll
        for (int n = 0; n < 4; ++n)
          acc[m][n] = __builtin_amdgcn_mfma_f32_16x16x32_bf16(a[m], b[n], acc[m][n], 0, 0, 0);
      __syncthreads();
      cur ^= 1;
    }
  }
  #undef STAGE_TILE

  const int rbase = bm + (wr << 6) + ((lane >> 4) << 2);
  const int cbase = bn + (wc << 6) + (lane & 15);

  if (pbuf) {
    long pstride = (long)(gridDim.y << 7) * ldc;
    float* pp = pbuf + ((long)z * stot + soff + s) * pstride;
    #pragma unroll
    for (int m = 0; m < 4; ++m)
      #pragma unroll
      for (int j = 0; j < 4; ++j) {
        int r = rbase + (m << 4) + j;
        #pragma unroll
        for (int n = 0; n < 4; ++n) {
          int cc = cbase + (n << 4);
          pp[(long)r * ldc + cc] = acc[m][n][j];
        }
      }
    return;
  }

  #pragma unroll
  for (int m = 0; m < 4; ++m) {
    #pragma unroll
    for (int j = 0; j < 4; ++j) {
      int r = rbase + (m << 4) + j;
      #pragma unroll
      for (int n = 0; n < 4; ++n) {
        int cc = cbase + (n << 4);
        float v = acc[m][n][j] * alpha;
        if (mode == 0) {
          if (Cadd) v += Cadd[(long)r * ldcadd + cc];
          if (causal && cc > r) v = NEG_BIG;
          C[(long)r * ldc + cc] = v;
        } else if (mode == 1) {
          float gg = Cadd[(long)r * ldcadd + cc];
          float sgv = gg / (1.f + expf(-gg));
          Cb[(long)r * ldc + cc] = f2bf(sgv * v);
        } else if (mode == 2) {
          Cb[(long)r * ldc + cc] = f2bf(v);
        } else {
          float gg = bf2f(CaddB[(long)r * ldcadd + cc]);
          float sgv = gg / (1.f + expf(-gg));
          Cb[(long)r * ldc + cc] = f2bf(sgv * v);
        }
      }
    }
  }
}

// ================= split-K reduce + epilogue =================
// mode 0: C(f32)=alpha*sum+Cadd; mode 1: Cb=silu(Cadd)*alpha*sum (bf16)
// mode 2: Cb = split3 A-layout bf16: row r stride 3*ldc; [hi | lo | hi] at +0/+ldc/+2*ldc
__global__ __launch_bounds__(256) void reduce_sk(
    const float* __restrict__ pbuf, long pstride, int S,
    float* __restrict__ C, u16* __restrict__ Cb, long csz, int ldc, int Nc,
    const float* __restrict__ Cadd, long caddsz, int ldcadd,
    float alpha, int mode) {
  const int z = blockIdx.y;
  const float* pz = pbuf + (long)z * S * pstride;
  long idx = ((long)blockIdx.x * 256 + threadIdx.x) * 8;
  long r = idx / Nc; int c = (int)(idx - r * Nc);
  float a[8] = {0.f, 0.f, 0.f, 0.f, 0.f, 0.f, 0.f, 0.f};
  for (int s = 0; s < S; ++s) {
    const float* pp = pz + (long)s * pstride + idx;
    float4 x = *(const float4*)pp;
    float4 y = *(const float4*)(pp + 4);
    a[0] += x.x; a[1] += x.y; a[2] += x.z; a[3] += x.w;
    a[4] += y.x; a[5] += y.y; a[6] += y.z; a[7] += y.w;
  }
  if (mode == 0) {
    long ob = (long)z * csz + r * ldc + c;
    #pragma unroll
    for (int k = 0; k < 8; ++k) {
      float v = a[k] * alpha;
      if (Cadd) v += Cadd[(long)z * caddsz + r * ldcadd + c + k];
      C[ob + k] = v;
    }
  } else if (mode == 1) {
    long ob = (long)z * csz + r * ldc + c;
    u16x8 o;
    #pragma unroll
    for (int k = 0; k < 8; ++k) {
      float gg = Cadd[(long)z * caddsz + r * ldcadd + c + k];
      float sgv = gg / (1.f + expf(-gg));
      o[k] = f2bf(sgv * a[k] * alpha);
    }
    *(u16x8*)&Cb[ob] = o;
  } else {
    long base = r * (3L * ldc) + (long)z * csz + c;
    u16x8 hv, lv;
    #pragma unroll
    for (int k = 0; k < 8; ++k) {
      u16 hi, lo; split2(a[k] * alpha, hi, lo);
      hv[k] = hi; lv[k] = lo;
    }
    *(u16x8*)&Cb[base] = hv;
    *(u16x8*)&Cb[base + ldc] = lv;
    *(u16x8*)&Cb[base + 2 * ldc] = hv;
  }
}

// ================= transpose f32 [K][N] -> plain bf16 [Npad][K] =================
__global__ __launch_bounds__(256) void transpose_f32_bf16(
    const float* __restrict__ src, long sbs, int ld_src, int Cvalid,
    u16* __restrict__ dst, long dbs, int ld_dst) {
  __shared__ float tile[64][65];
  src += (long)blockIdx.z * sbs; dst += (long)blockIdx.z * dbs;
  const int c0 = blockIdx.x << 6, r0 = blockIdx.y << 6;
  const int tid = threadIdx.x;
  const int tc = (tid & 15) << 2, tr0 = tid >> 4;
  const bool valid = c0 < Cvalid;
  #pragma unroll
  for (int i = 0; i < 4; ++i) {
    int r = tr0 + (i << 4);
    float4 v;
    if (valid) v = *(const float4*)&src[(long)(r0 + r) * ld_src + c0 + tc];
    else { v.x = 0.f; v.y = 0.f; v.z = 0.f; v.w = 0.f; }
    tile[r][tc] = v.x; tile[r][tc + 1] = v.y; tile[r][tc + 2] = v.z; tile[r][tc + 3] = v.w;
  }
  __syncthreads();
  const int oc = tid >> 2, seg = tid & 3;
  u16x8 o0, o1;
  #pragma unroll
  for (int k = 0; k < 8; ++k) o0[k] = f2bf(tile[(seg << 4) + k][oc]);
  #pragma unroll
  for (int k = 0; k < 8; ++k) o1[k] = f2bf(tile[(seg << 4) + 8 + k][oc]);
  u16* dp = &dst[(long)(c0 + oc) * ld_dst + r0 + (seg << 4)];
  *(u16x8*)dp = o0;
  *(u16x8*)(dp + 8) = o1;
}

// ================= transpose f32 [K][N] -> split3 B-side bf16 [Npad][3K] = [hi|hi|lo] =================
__global__ __launch_bounds__(256) void transpose_split3(
    const float* __restrict__ src, long sbs, int ld_src, int Cvalid,
    u16* __restrict__ dst, long dbs, int Kp) {
  __shared__ float tile[64][65];
  src += (long)blockIdx.z * sbs; dst += (long)blockIdx.z * dbs;
  const int c0 = blockIdx.x << 6, r0 = blockIdx.y << 6;
  const int tid = threadIdx.x;
  const int tc = (tid & 15) << 2, tr0 = tid >> 4;
  const bool valid = c0 < Cvalid;
  #pragma unroll
  for (int i = 0; i < 4; ++i) {
    int r = tr0 + (i << 4);
    float4 v;
    if (valid) v = *(const float4*)&src[(long)(r0 + r) * ld_src + c0 + tc];
    else { v.x = 0.f; v.y = 0.f; v.z = 0.f; v.w = 0.f; }
    tile[r][tc] = v.x; tile[r][tc + 1] = v.y; tile[r][tc + 2] = v.z; tile[r][tc + 3] = v.w;
  }
  __syncthreads();
  const int oc = tid >> 2, seg = tid & 3;
  u16x8 h0, h1, l0, l1;
  #pragma unroll
  for (int k = 0; k < 8; ++k) {
    u16 hi, lo; split2(tile[(seg << 4) + k][oc], hi, lo);
    h0[k] = hi; l0[k] = lo;
  }
  #pragma unroll
  for (int k = 0; k < 8; ++k) {
    u16 hi, lo; split2(tile[(seg << 4) + 8 + k][oc], hi, lo);
    h1[k] = hi; l1[k] = lo;
  }
  const int ldd = 3 * Kp;
  u16* dp = &dst[(long)(c0 + oc) * ldd + r0 + (seg << 4)];
  *(u16x8*)dp = h0;            *(u16x8*)(dp + 8) = h1;
  *(u16x8*)(dp + Kp) = h0;     *(u16x8*)(dp + Kp + 8) = h1;
  *(u16x8*)(dp + 2 * Kp) = l0; *(u16x8*)(dp + 2 * Kp + 8) = l1;
}

// ================= add + RMS -> resid1(f32), h3(split3 A-side) =================
__global__ __launch_bounds__(256) void add_rms_kernel(
    const float* __restrict__ hs, const float* __restrict__ res,
    const float* __restrict__ w, float* __restrict__ resid1, u16* __restrict__ h3) {
  __shared__ float sbuf[4];
  int t = blockIdx.x;
  float v[8]; float ss = 0.f;
  #pragma unroll
  for (int i = 0; i < 8; ++i) {
    int j = threadIdx.x + (i << 8);
    float x = hs[(long)t * HID + j] + res[(long)t * HID + j];
    v[i] = x; resid1[(long)t * HID + j] = x; ss += x * x;
  }
  ss = block_sum(ss, sbuf);
  float sc = rsqrtf(ss / (float)HID + EPSF);
  u16* base = h3 + (long)t * (3 * HID);
  #pragma unroll
  for (int i = 0; i < 8; ++i) {
    int j = threadIdx.x + (i << 8);
    u16 hi, lo; split2(v[i] * sc * w[j], hi, lo);
    base[j] = hi; base[HID + j] = lo; base[2 * HID + j] = hi;
  }
}

// ================= row RMS -> split3 or plain bf16 (+f32) =================
template <int NW, bool SPLIT, bool WF32>
__global__ __launch_bounds__(256) void rms_rows_kernel(
    const float* __restrict__ in, int ldin, const float* __restrict__ w,
    u16* __restrict__ outb, float* __restrict__ outf) {
  __shared__ float sbuf[4];
  int t = blockIdx.x;
  const int W = NW * 256;
  float v[NW]; float ss = 0.f;
  #pragma unroll
  for (int i = 0; i < NW; ++i) {
    int j = threadIdx.x + (i << 8);
    float x = in[(long)t * ldin + j];
    v[i] = x; ss += x * x;
  }
  ss = block_sum(ss, sbuf);
  float sc = rsqrtf(ss / (float)W + EPSF);
  #pragma unroll
  for (int i = 0; i < NW; ++i) {
    int j = threadIdx.x + (i << 8);
    float y = v[i] * sc * w[j];
    if (SPLIT) {
      u16 hi, lo; split2(y, hi, lo);
      u16* base = outb + (long)t * (3 * W);
      base[j] = hi; base[W + j] = lo; base[2 * W + j] = hi;
    } else {
      outb[(long)t * W + j] = f2bf(y);
    }
    if (WF32) outf[(long)t * W + j] = y;
  }
}

// ================= RoPE (f32, in place on qbuf; qkv k_pe -> kpe) =================
__global__ __launch_bounds__(256) void rope_kernel(
    const int* __restrict__ pos, float* __restrict__ q,
    const float* __restrict__ qkv, float* __restrict__ kpe) {
  int t = blockIdx.x;
  float fp = (float)pos[t];
  for (int item = threadIdx.x; item < 544; item += 256) {
    int i = item & 31;
    float inv = expf(-((float)i * (2.f / 64.f)) * 9.210340371976184f);
    float ang = fp * inv;
    float c = cosf(ang), s = sinf(ang);
    if (item < 512) {
      int hh = item >> 5;
      long base = (long)t * (HEADS * QD) + hh * QD + NOPE;
      float x1 = q[base + i], x2 = q[base + 32 + i];
      q[base + i] = x1 * c - x2 * s;
      q[base + 32 + i] = x2 * c + x1 * s;
    } else {
      long base = (long)t * QKV_LD + (Q_LORA + KV_LORA);
      float x1 = qkv[base + i], x2 = qkv[base + 32 + i];
      kpe[(long)t * 64 + i] = x1 * c - x2 * s;
      kpe[(long)t * 64 + 32 + i] = x2 * c + x1 * s;
    }
  }
}

// ================= q3 per head: A-side [16][T][3*192] = [hi|lo|hi] =================
__global__ __launch_bounds__(192) void build_q3_kernel(
    const float* __restrict__ qbuf, u16* __restrict__ q3) {
  int t = blockIdx.x, h = blockIdx.y, d = threadIdx.x;
  float x = qbuf[(long)t * (HEADS * QD) + h * QD + d];
  u16 hi, lo; split2(x, hi, lo);
  u16* base = q3 + ((long)h * T_TOK + t) * (3 * QD);
  base[d] = hi; base[QD + d] = lo; base[2 * QD + d] = hi;
}

// ================= kmat3 per head: B-side [16][T][3*192] = [hi|hi|lo] =================
__global__ __launch_bounds__(192) void build_kmat3_kernel(
    const float* __restrict__ kv, const float* __restrict__ kpe,
    u16* __restrict__ kmat3) {
  int t = blockIdx.x, h = blockIdx.y, d = threadIdx.x;
  float v = (d < NOPE) ? kv[(long)t * (HEADS * KVD) + h * KVD + d]
                       : kpe[(long)t * 64 + (d - NOPE)];
  u16 hi, lo; split2(v, hi, lo);
  u16* base = kmat3 + ((long)h * T_TOK + t) * (3 * QD);
  base[d] = hi; base[QD + d] = hi; base[2 * QD + d] = lo;
}

// ================= masked softmax row -> P2 [row][2*1024] = [hi|lo] (prefix-only loads) =================
__global__ __launch_bounds__(256) void softmax_kernel(
    const float* __restrict__ S, u16* __restrict__ P2) {
  __shared__ float sbuf[4];
  long row = blockIdx.x;
  int r = (int)(row & (T_TOK - 1));
  const float* p = S + row * T_TOK;
  int c0 = threadIdx.x << 2;
  float4 v;
  if (c0 <= r) {
    v = ((const float4*)p)[threadIdx.x];
    if (c0 + 1 > r) v.y = NEG_BIG;
    if (c0 + 2 > r) v.z = NEG_BIG;
    if (c0 + 3 > r) v.w = NEG_BIG;
  } else {
    v.x = NEG_BIG; v.y = NEG_BIG; v.z = NEG_BIG; v.w = NEG_BIG;
  }
  float m = fmaxf(fmaxf(v.x, v.y), fmaxf(v.z, v.w));
  m = block_max(m, sbuf);
  v.x = expf(v.x - m); v.y = expf(v.y - m); v.z = expf(v.z - m); v.w = expf(v.w - m);
  float s = v.x + v.y + v.z + v.w;
  s = block_sum(s, sbuf);
  float inv = 1.f / s;
  u16x4 hv, lv;
  u16 hi, lo;
  split2(v.x * inv, hi, lo); hv[0] = hi; lv[0] = lo;
  split2(v.y * inv, hi, lo); hv[1] = hi; lv[1] = lo;
  split2(v.z * inv, hi, lo); hv[2] = hi; lv[2] = lo;
  split2(v.w * inv, hi, lo); hv[3] = hi; lv[3] = lo;
  u16* base = P2 + row * (2 * T_TOK) + (threadIdx.x << 2);
  *(u16x4*)base = hv;
  *(u16x4*)(base + T_TOK) = lv;
}

// ================= gate + top-2 -> ti[t][2], tw[t][2] =================
__global__ __launch_bounds__(256) void gate_topk_kernel(
    const float* __restrict__ h2, const float* __restrict__ gw,
    int* __restrict__ ti, float* __restrict__ tw) {
  __shared__ float sbuf[4];
  __shared__ float lg[N_EXP];
  int t = blockIdx.x;
  float p[N_EXP] = {0.f, 0.f, 0.f, 0.f, 0.f, 0.f, 0.f, 0.f};
  for (int j = threadIdx.x; j < HID; j += 256) {
    float x = h2[(long)t * HID + j];
    const float* gr = gw + (long)j * N_EXP;
    #pragma unroll
    for (int e = 0; e < N_EXP; ++e) p[e] += x * gr[e];
  }
  #pragma unroll
  for (int e = 0; e < N_EXP; ++e) {
    float s = block_sum(p[e], sbuf);
    if (threadIdx.x == 0) lg[e] = s;
  }
  __syncthreads();
  if (threadIdx.x == 0) {
    float m = lg[0];
    for (int e = 1; e < N_EXP; ++e) m = fmaxf(m, lg[e]);
    float pe[N_EXP]; float s = 0.f;
    for (int e = 0; e < N_EXP; ++e) { pe[e] = expf(lg[e] - m); s += pe[e]; }
    for (int e = 0; e < N_EXP; ++e) pe[e] /= s;
    int i0 = 0;
    for (int e = 1; e < N_EXP; ++e) if (pe[e] > pe[i0]) i0 = e;
    int i1 = -1;
    for (int e = 0; e < N_EXP; ++e) if (e != i0 && (i1 < 0 || pe[e] > pe[i1])) i1 = e;
    float ssum = pe[i0] + pe[i1];
    ti[2 * t] = i0; ti[2 * t + 1] = i1;
    tw[2 * t] = pe[i0] / ssum; tw[2 * t + 1] = pe[i1] / ssum;
  }
}

// ================= routing lists for 20 z-slices (z and z+10 identical): tokidx20, cnt20, pos =================
__global__ __launch_bounds__(64) void route_build_kernel(
    const int* __restrict__ ti, int* __restrict__ tokidx,
    int* __restrict__ pos, int* __restrict__ cnt) {
  int e = blockIdx.x;            // 0..19
  int le = (e < 10) ? e : e - 10;
  int lane = threadIdx.x;
  if (le >= N_EXP) {  // shared virtual experts: identity
    for (int p = lane; p < T_TOK; p += 64) tokidx[(long)e * T_TOK + p] = p;
    if (lane == 0) cnt[e] = T_TOK;
    return;
  }
  int c = 0;
  for (int base = 0; base < T_TOK; base += 64) {
    int t = base + lane;
    int e0 = ti[2 * t], e1 = ti[2 * t + 1];
    bool match = (e0 == le) || (e1 == le);
    unsigned long long mask = __ballot(match);
    int pref = __popcll(mask & ((1ull << lane) - 1ull));
    if (match) {
      int p = c + pref;
      tokidx[(long)e * T_TOK + p] = t;
      if (e < 10) pos[2 * t + ((e0 == le) ? 0 : 1)] = p;
    }
    c += __popcll(mask);
  }
  for (int p = c + lane; p < T_TOK; p += 64) tokidx[(long)e * T_TOK + p] = 0;
  if (lane == 0) cnt[e] = c;
}

// ================= silu over split gate|up z-slices: gact[e][r][i] = silu(gug[e][r][i]) * gug[e+10][r][i] =================
__global__ __launch_bounds__(256) void silu_mul_moe_kernel(
    const u16* __restrict__ gug, const int* __restrict__ cnt,
    u16* __restrict__ gact) {
  int r = blockIdx.x, e = blockIdx.y;
  int padded = (cnt[e] + 127) & ~127;
  if (r >= padded) return;
  int j = threadIdx.x << 3;
  if (j >= MOE_I) return;
  u16x8 gv = *(const u16x8*)&gug[((long)e * T_TOK + r) * MOE_I + j];
  u16x8 uv = *(const u16x8*)&gug[(((long)e + 10) * T_TOK + r) * MOE_I + j];
  u16x8 o;
  #pragma unroll
  for (int k = 0; k < 8; ++k) {
    float g = bf2f(gv[k]);
    o[k] = f2bf(g / (1.f + expf(-g)) * bf2f(uv[k]));
  }
  *(u16x8*)&gact[((long)e * T_TOK + r) * MOE_I + j] = o;
}

// ================= out0[t] = tw0*y[e0][p0] + tw1*y[e1][p1] + y[8][t] + y[9][t] =================
__global__ __launch_bounds__(256) void combine_out_kernel(
    const u16* __restrict__ y, const int* __restrict__ ti,
    const float* __restrict__ tw, const int* __restrict__ pos,
    float* __restrict__ out0) {
  int t = blockIdx.x;
  int j = threadIdx.x << 3;
  int e0 = ti[2 * t], e1 = ti[2 * t + 1];
  int p0 = pos[2 * t], p1 = pos[2 * t + 1];
  float w0 = tw[2 * t], w1 = tw[2 * t + 1];
  u16x8 a = *(const u16x8*)&y[((long)e0 * T_TOK + p0) * HID + j];
  u16x8 b = *(const u16x8*)&y[((long)e1 * T_TOK + p1) * HID + j];
  u16x8 c = *(const u16x8*)&y[((long)8 * T_TOK + t) * HID + j];
  u16x8 d = *(const u16x8*)&y[((long)9 * T_TOK + t) * HID + j];
  float* rp = out0 + (long)t * HID + j;
  #pragma unroll
  for (int k = 0; k < 8; ++k)
    rp[k] = w0 * bf2f(a[k]) + w1 * bf2f(b[k]) + bf2f(c[k]) + bf2f(d[k]);
}

// ================= launcher =================
extern "C" void kernel_launch(void* const* d_in, const int* in_sizes, int n_in,
                              void* d_out, int out_size, void* d_ws, size_t ws_size,
                              hipStream_t stream) {
  (void)in_sizes; (void)n_in; (void)out_size; (void)ws_size;
  const int*   positions = (const int*)d_in[0];
  const float* hs        = (const float*)d_in[1];
  const float* res       = (const float*)d_in[2];
  const float* w_in_ln   = (const float*)d_in[3];
  const float* w_post_ln = (const float*)d_in[4];
  const float* w_q_ln    = (const float*)d_in[5];
  const float* w_kv_ln   = (const float*)d_in[6];
  const float* w_qkv_a   = (const float*)d_in[7];
  const float* w_q_b     = (const float*)d_in[8];
  const float* w_kv_b    = (const float*)d_in[9];
  const float* w_o       = (const float*)d_in[10];
  const float* gate_w    = (const float*)d_in[11];
  const float* we_gate   = (const float*)d_in[12];
  const float* we_up     = (const float*)d_in[13];
  const float* we_down   = (const float*)d_in[14];
  const float* ws_gate   = (const float*)d_in[15];
  const float* ws_up     = (const float*)d_in[16];
  const float* ws_dn     = (const float*)d_in[17];

  float* out0   = (float*)d_out;
  float* resid2 = out0 + (long)T_TOK * HID;

  char* Wb = (char*)d_ws;
  size_t off = 0;
  #define CARVE(name, type, bytes) type* name = (type*)(Wb + off); off += (((size_t)(bytes) + 255) & ~(size_t)255)

  // ---- W1: persistent split3 attention weights ----
  CARVE(wqkvaT3, u16, (size_t)QKV_LD * 3 * HID * 2);
  CARVE(wqbT3,   u16, (size_t)(HEADS * QD) * 3 * Q_LORA * 2);
  CARVE(wkvbT3,  u16, (size_t)(HEADS * KVD) * 3 * KV_LORA * 2);
  CARVE(woT3,    u16, (size_t)HID * 3 * HID * 2);

  size_t pool = off;
  // ---- phase A scratch ----
  CARVE(resid1, float, (size_t)T_TOK * HID * 4);
  CARVE(h3,     u16,   (size_t)T_TOK * 3 * HID * 2);
  CARVE(qkv,    float, (size_t)T_TOK * QKV_LD * 4);
  CARVE(qc3,    u16,   (size_t)T_TOK * 3 * Q_LORA * 2);
  CARVE(kvc3,   u16,   (size_t)T_TOK * 3 * KV_LORA * 2);
  CARVE(qbuf,   float, (size_t)T_TOK * HEADS * QD * 4);
  CARVE(q3,     u16,   (size_t)HEADS * T_TOK * 3 * QD * 2);
  CARVE(kvbuf,  float, (size_t)T_TOK * HEADS * KVD * 4);
  CARVE(kpe,    float, (size_t)T_TOK * 64 * 4);
  CARVE(kmat3,  u16,   (size_t)HEADS * T_TOK * 3 * QD * 2);
  CARVE(vt3,    u16,   (size_t)HEADS * VD * 3 * T_TOK * 2);
  CARVE(scores, float, (size_t)HEADS * T_TOK * T_TOK * 4);   // doubles as phase-A split-K pbuf
  CARVE(P2,     u16,   (size_t)HEADS * T_TOK * 2 * T_TOK * 2);
  CARVE(attn3,  u16,   (size_t)T_TOK * 3 * HID * 2);
  size_t endA = off;
  float* pbufA = scores;

  // ---- phase B (aliases phase A; written only after step 11) ----
  off = pool;
  CARVE(wegu20, u16, (size_t)20 * MOE_I * HID * 2);   // [0..9]=gate (8 routed + 2 shared), [10..19]=up
  CARVE(wedT10, u16, (size_t)10 * HID * MOE_I * 2);
  CARVE(h2,     float, (size_t)T_TOK * HID * 4);
  CARVE(h2_b,   u16,   (size_t)T_TOK * HID * 2);
  CARVE(ti,     int,   (size_t)T_TOK * 2 * 4);
  CARVE(tw,     float, (size_t)T_TOK * 2 * 4);
  CARVE(pos,    int,   (size_t)T_TOK * 2 * 4);
  CARVE(tokidx20, int, (size_t)20 * T_TOK * 4);
  CARVE(cnt20,  int,   128);
  CARVE(gug20,  u16,   (size_t)20 * T_TOK * MOE_I * 2);
  CARVE(gact,   u16,   (size_t)10 * T_TOK * MOE_I * 2);
  CARVE(ycomp,  u16,   (size_t)10 * T_TOK * HID * 2);
  if (off < endA) off = endA;
  #undef CARVE

  u16* wegT10 = wegu20;                                  // gate slices
  u16* weuT10 = wegu20 + (size_t)10 * MOE_I * HID;       // up slices

  const float* nullf = nullptr;
  float* nullC = nullptr;
  u16* nullB = nullptr;
  const u16* nullBB = nullptr;
  const int* nullI = nullptr;

  // ---- 0. attention weight transposes (split3) ----
  hipLaunchKernelGGL(transpose_split3, dim3(QKV_LD / 64, HID / 64, 1), dim3(256), 0, stream,
                     w_qkv_a, 0L, QKV_N, QKV_N, wqkvaT3, 0L, HID);
  hipLaunchKernelGGL(transpose_split3, dim3(HEADS * QD / 64, Q_LORA / 64, 1), dim3(256), 0, stream,
                     w_q_b, 0L, HEADS * QD, HEADS * QD, wqbT3, 0L, Q_LORA);
  hipLaunchKernelGGL(transpose_split3, dim3(HEADS * KVD / 64, KV_LORA / 64, 1), dim3(256), 0, stream,
                     w_kv_b, 0L, HEADS * KVD, HEADS * KVD, wkvbT3, 0L, KV_LORA);
  hipLaunchKernelGGL(transpose_split3, dim3(HID / 64, HID / 64, 1), dim3(256), 0, stream,
                     w_o, 0L, HID, HID, woT3, 0L, HID);

  // ---- 1. resid1 = hs+res; h3 = split3(rms) ----
  hipLaunchKernelGGL(add_rms_kernel, dim3(T_TOK), dim3(256), 0, stream,
                     hs, res, w_in_ln, resid1, h3);
  // ---- 2. qkv = h @ w_qkv_a (split3 K'=6144, split-K 4) ----
  hipLaunchKernelGGL(gemm_bf16, dim3(QKV_LD / 128, T_TOK / 128, 4), dim3(256), 0, stream,
                     h3, 0L, 3 * HID, wqkvaT3, 0L, 3 * HID,
                     nullC, nullB, 0L, QKV_LD, nullf, nullBB, 0, 3 * HID, 1.f, 0, 0,
                     pbufA, 4, 4, 0, nullI, nullI, 0, 0);
  hipLaunchKernelGGL(reduce_sk, dim3(T_TOK * QKV_LD / 2048, 1), dim3(256), 0, stream,
                     pbufA, (long)T_TOK * QKV_LD, 4,
                     qkv, nullB, 0L, QKV_LD, QKV_LD, nullf, 0L, 0, 1.f, 0);
  // ---- 3. q_c, kv_c RMS -> split3 ----
  hipLaunchKernelGGL((rms_rows_kernel<6, true, false>), dim3(T_TOK), dim3(256), 0, stream,
                     qkv, QKV_LD, w_q_ln, qc3, (float*)nullptr);
  hipLaunchKernelGGL((rms_rows_kernel<2, true, false>), dim3(T_TOK), dim3(256), 0, stream,
                     qkv + Q_LORA, QKV_LD, w_kv_ln, kvc3, (float*)nullptr);
  // ---- 4. q = q_c @ w_q_b (split3 K'=4608, split-K 4) ----
  hipLaunchKernelGGL(gemm_bf16, dim3(HEADS * QD / 128, T_TOK / 128, 4), dim3(256), 0, stream,
                     qc3, 0L, 3 * Q_LORA, wqbT3, 0L, 3 * Q_LORA,
                     nullC, nullB, 0L, HEADS * QD, nullf, nullBB, 0, 3 * Q_LORA, 1.f, 0, 0,
                     pbufA, 4, 4, 0, nullI, nullI, 0, 0);
  hipLaunchKernelGGL(reduce_sk, dim3(T_TOK * HEADS * QD / 2048, 1), dim3(256), 0, stream,
                     pbufA, (long)T_TOK * HEADS * QD, 4,
                     qbuf, nullB, 0L, HEADS * QD, HEADS * QD, nullf, 0L, 0, 1.f, 0);
  // ---- 5. kv = kv_c @ w_kv_b (split3 K'=1536, split-K 4) ----
  hipLaunchKernelGGL(gemm_bf16, dim3(HEADS * KVD / 128, T_TOK / 128, 4), dim3(256), 0, stream,
                     kvc3, 0L, 3 * KV_LORA, wkvbT3, 0L, 3 * KV_LORA,
                     nullC, nullB, 0L, HEADS * KVD, nullf, nullBB, 0, 3 * KV_LORA, 1.f, 0, 0,
                     pbufA, 4, 4, 0, nullI, nullI, 0, 0);
  hipLaunchKernelGGL(reduce_sk, dim3(T_TOK * HEADS * KVD / 2048, 1), dim3(256), 0, stream,
                     pbufA, (long)T_TOK * HEADS * KVD, 4,
                     kvbuf, nullB, 0L, HEADS * KVD, HEADS * KVD, nullf, 0L, 0, 1.f, 0);
  // ---- 6. RoPE ----
  hipLaunchKernelGGL(rope_kernel, dim3(T_TOK), dim3(256), 0, stream,
                     positions, qbuf, qkv, kpe);
  // ---- 7. q3, kmat3, vt3 ----
  hipLaunchKernelGGL(build_q3_kernel, dim3(T_TOK, HEADS), dim3(192), 0, stream, qbuf, q3);
  hipLaunchKernelGGL(build_kmat3_kernel, dim3(T_TOK, HEADS), dim3(192), 0, stream,
                     kvbuf, kpe, kmat3);
  hipLaunchKernelGGL(transpose_split3, dim3(VD / 64, T_TOK / 64, HEADS), dim3(256), 0, stream,
                     kvbuf + NOPE, 256L, HEADS * KVD, VD, vt3, (long)VD * 3 * T_TOK, T_TOK);
  // ---- 8. scores (split3 K'=576, causal; masked tiles skipped) ----
  hipLaunchKernelGGL(gemm_bf16, dim3(T_TOK / 128, T_TOK / 128, HEADS), dim3(256), 0, stream,
                     q3, (long)T_TOK * 3 * QD, 3 * QD,
                     kmat3, (long)T_TOK * 3 * QD, 3 * QD,
                     scores, nullB, (long)T_TOK * T_TOK, T_TOK,
                     nullf, nullBB, 0, 576, 0.07216878364870322f, 1, 0,
                     nullC, 1, 1, 0, nullI, nullI, 0, 0);
  // ---- 9. masked softmax (prefix-only reads) -> P2 [hi|lo] ----
  hipLaunchKernelGGL(softmax_kernel, dim3(HEADS * T_TOK), dim3(256), 0, stream, scores, P2);
  // ---- 10. PV with causal K-clamp: [ph|pl]@[vh|vh] (K=2048, S=4) + ph@vl (K=1024, S=2) ----
  hipLaunchKernelGGL(gemm_bf16, dim3(VD / 128, T_TOK / 128, HEADS * 4), dim3(256), 0, stream,
                     P2, (long)T_TOK * 2 * T_TOK, 2 * T_TOK,
                     vt3, (long)VD * 3 * T_TOK, 3 * T_TOK,
                     nullC, nullB, 0L, VD, nullf, nullBB, 0, 2 * T_TOK, 1.f, 0, 0,
                     pbufA, 4, 6, 0, nullI, nullI, 1, 0);
  hipLaunchKernelGGL(gemm_bf16, dim3(VD / 128, T_TOK / 128, HEADS * 2), dim3(256), 0, stream,
                     P2, (long)T_TOK * 2 * T_TOK, 2 * T_TOK,
                     vt3 + 2 * T_TOK, (long)VD * 3 * T_TOK, 3 * T_TOK,
                     nullC, nullB, 0L, VD, nullf, nullBB, 0, T_TOK, 1.f, 0, 0,
                     pbufA, 2, 6, 4, nullI, nullI, 1, 0);
  // reduce writes attn3 (split3 A-layout) directly: mode 2
  hipLaunchKernelGGL(reduce_sk, dim3(T_TOK * VD / 2048, HEADS), dim3(256), 0, stream,
                     pbufA, (long)T_TOK * VD, 6,
                     nullC, attn3, (long)VD, HID, VD, nullf, 0L, 0, 1.f, 2);
  // ---- 11. resid2 = resid1 + attn @ w_o (split3 K'=6144, split-K 4) ----
  hipLaunchKernelGGL(gemm_bf16, dim3(HID / 128, T_TOK / 128, 4), dim3(256), 0, stream,
                     attn3, 0L, 3 * HID, woT3, 0L, 3 * HID,
                     nullC, nullB, 0L, HID, nullf, nullBB, 0, 3 * HID, 1.f, 0, 0,
                     pbufA, 4, 4, 0, nullI, nullI, 0, 0);
  hipLaunchKernelGGL(reduce_sk, dim3(T_TOK * HID / 2048, 1), dim3(256), 0, stream,
                     pbufA, (long)T_TOK * HID, 4,
                     resid2, nullB, 0L, HID, HID, resid1, 0L, HID, 1.f, 0);

  // ---- phase-B weight transposes: [gate×10 | up×10] + down×10 ----
  hipLaunchKernelGGL(transpose_f32_bf16, dim3(MOE_I / 64, HID / 64, N_EXP), dim3(256), 0, stream,
                     we_gate, (long)HID * MOE_I, MOE_I, MOE_I, wegT10, (long)MOE_I * HID, HID);
  hipLaunchKernelGGL(transpose_f32_bf16, dim3(MOE_I / 64, HID / 64, 2), dim3(256), 0, stream,
                     ws_gate, (long)MOE_I, SH_I, MOE_I,
                     wegT10 + (size_t)8 * MOE_I * HID, (long)MOE_I * HID, HID);
  hipLaunchKernelGGL(transpose_f32_bf16, dim3(MOE_I / 64, HID / 64, N_EXP), dim3(256), 0, stream,
                     we_up, (long)HID * MOE_I, MOE_I, MOE_I, weuT10, (long)MOE_I * HID, HID);
  hipLaunchKernelGGL(transpose_f32_bf16, dim3(MOE_I / 64, HID / 64, 2), dim3(256), 0, stream,
                     ws_up, (long)MOE_I, SH_I, MOE_I,
                     weuT10 + (size_t)8 * MOE_I * HID, (long)MOE_I * HID, HID);
  hipLaunchKernelGGL(transpose_f32_bf16, dim3(HID / 64, MOE_I / 64, N_EXP), dim3(256), 0, stream,
                     we_down, (long)MOE_I * HID, HID, HID, wedT10, (long)HID * MOE_I, MOE_I);
  hipLaunchKernelGGL(transpose_f32_bf16, dim3(HID / 64, MOE_I / 64, 2), dim3(256), 0, stream,
                     ws_dn, (long)MOE_I * HID, HID, HID,
                     wedT10 + (size_t)8 * HID * MOE_I, (long)HID * MOE_I, MOE_I);

  // ---- 12. h2 = rms(resid2) ----
  hipLaunchKernelGGL((rms_rows_kernel<8, false, true>), dim3(T_TOK), dim3(256), 0, stream,
                     resid2, HID, w_post_ln, h2_b, h2);
  // ---- 13. gating + routing lists (20 z-slices) ----
  hipLaunchKernelGGL(gate_topk_kernel, dim3(T_TOK), dim3(256), 0, stream,
                     h2, gate_w, ti, tw);
  hipLaunchKernelGGL(route_build_kernel, dim3(20), dim3(64), 0, stream,
                     ti, tokidx20, pos, cnt20);
  // ---- 14. gate+up in ONE 20-z launch (mode 2, gathered, pair-balanced swizzle) -> gug20; silu -> gact ----
  hipLaunchKernelGGL(gemm_bf16, dim3(MOE_I / 128, T_TOK / 128, 20), dim3(256), 0, stream,
                     h2_b, 0L, HID, wegu20, (long)MOE_I * HID, HID,
                     nullC, gug20, (long)T_TOK * MOE_I, MOE_I,
                     nullf, nullBB, 0, HID, 1.f, 0, 2, nullC, 1, 1, 0, tokidx20, cnt20, 0, 1);
  hipLaunchKernelGGL(silu_mul_moe_kernel, dim3(T_TOK, 10), dim3(256), 0, stream,
                     gug20, cnt20, gact);
  // ---- 15. down over compact rows -> ycomp (mode 2, cnt-guarded, pair-balanced swizzle) ----
  hipLaunchKernelGGL(gemm_bf16, dim3(HID / 128, T_TOK / 128, 10), dim3(256), 0, stream,
                     gact, (long)T_TOK * MOE_I, MOE_I,
                     wedT10, (long)HID * MOE_I, MOE_I,
                     nullC, ycomp, (long)T_TOK * HID, HID,
                     nullf, nullBB, 0, MOE_I, 1.f, 0, 2, nullC, 1, 1, 0, nullI, cnt20, 0, 1);
  // ---- 16. combine: out0 = tw0*y[e0][p0] + tw1*y[e1][p1] + y8 + y9 ----
  hipLaunchKernelGGL(combine_out_kernel, dim3(T_TOK), dim3(256), 0, stream,
                     ycomp, ti, tw, pos, out0);
}